// Round 11
// baseline (1022.190 us; speedup 1.0000x reference)
//
#include <hip/hip_runtime.h>
#include <hip/hip_bf16.h>
#include <math.h>

#define T_DIM 4096
#define HSZ   7168
#define QLR_K 1536
#define NH    64
#define HD    128
#define QN    (NH*HD)   // 8192
#define TOPK_N 2048
#define MASK_VAL (-3.0e38f)
// 0.125 (w_proj scale) * 128^-0.5 (q scale, folded out of fp8 q for precision)
#define WSCALE 0.011048543456039806f

using short8 = __attribute__((ext_vector_type(8))) short;   // 8 bf16 (4 VGPR)
using f32x4  = __attribute__((ext_vector_type(4))) float;

#define MFMA16(a,b,c) __builtin_amdgcn_mfma_f32_16x16x32_bf16(a,b,c,0,0,0)
#define MFMA8(a,b,c)  __builtin_amdgcn_mfma_f32_16x16x32_fp8_fp8(a,b,c,0,0,0)

__device__ __forceinline__ float rope_invf(int d) {
    return (float)(1.0 / pow(10000.0, (double)d / 32.0));
}
__device__ __forceinline__ unsigned short f2bf(float f) {
    unsigned u = __float_as_uint(f);
    return (unsigned short)((u + 0x7FFFu + ((u >> 16) & 1u)) >> 16);
}
// HW fp8 e4m3 conversion (v_cvt_pk_fp8_f32, gfx940+)
__device__ __forceinline__ unsigned char f2fp8(float x) {
    return (unsigned char)(__builtin_amdgcn_cvt_pk_fp8_f32(x, x, 0, false) & 0xFF);
}
__device__ __forceinline__ unsigned pk4fp8(float a, float b, float c, float d) {
    unsigned w = (unsigned)__builtin_amdgcn_cvt_pk_fp8_f32(a, b, 0, false);
    return (unsigned)__builtin_amdgcn_cvt_pk_fp8_f32(c, d, (int)w, true);
}

// ============================================================================
// rope_tab
// ============================================================================
__global__ __launch_bounds__(256)
void rope_tab_kernel(const int* __restrict__ positions, float2* __restrict__ tab) {
    int idx = blockIdx.x * 256 + threadIdx.x;
    int t = idx >> 5, dd = idx & 31;
    float p = (float)positions[t];
    float ang = p * rope_invf(dd);
    float s, c; sincosf(ang, &s, &c);
    tab[idx] = make_float2(c, s);
}

// ============================================================================
// conv_afrag (bf16, for hs -> kw path)
// ============================================================================
__global__ __launch_bounds__(256)
void conv_afrag(const float* __restrict__ src, unsigned short* __restrict__ dst,
                int C, int KS, int ctiles) {
    __shared__ float lds[32][258];
    const int tid = threadIdx.x;
    const int rt = blockIdx.x / ctiles, ct = blockIdx.x - rt * ctiles;
    const int r0 = rt * 32, c0 = ct * 256;
#pragma unroll
    for (int it = 0; it < 8; ++it) {
        int fid = it * 256 + tid;
        int r = fid >> 6, c4 = (fid & 63) << 2;
        float4 v = *(const float4*)(src + (size_t)(r0 + r) * C + c0 + c4);
        lds[r][c4] = v.x; lds[r][c4 + 1] = v.y; lds[r][c4 + 2] = v.z; lds[r][c4 + 3] = v.w;
    }
    __syncthreads();
    const int lane = tid & 63, wid = tid >> 6;
#pragma unroll
    for (int j = 0; j < 4; ++j) {
        int s = wid * 4 + j;
        int ig_l = s >> 3, ks_l = s & 7;
        int r = ig_l * 16 + (lane & 15);
        int c = ks_l * 32 + ((lane >> 4) << 3);
        unsigned short o[8];
#pragma unroll
        for (int e = 0; e < 8; ++e) o[e] = f2bf(lds[r][c + e]);
        size_t ig = rt * 2 + ig_l, ks = (size_t)ct * 8 + ks_l;
        *(short8*)(dst + ((ig * KS + ks) * 64 + lane) * 8) = *(short8*)o;
    }
}

// ============================================================================
// conv_qr_fp8
// ============================================================================
__global__ __launch_bounds__(256)
void conv_qr_fp8(const float* __restrict__ src, unsigned char* __restrict__ dst) {
    __shared__ float lds[32][258];
    const int tid = threadIdx.x;
    const int rt = blockIdx.x / 6, ct = blockIdx.x - rt * 6;
    const int r0 = rt * 32, c0 = ct * 256;
#pragma unroll
    for (int it = 0; it < 8; ++it) {
        int fid = it * 256 + tid;
        int r = fid >> 6, c4 = (fid & 63) << 2;
        float4 v = *(const float4*)(src + (size_t)(r0 + r) * QLR_K + c0 + c4);
        lds[r][c4] = v.x; lds[r][c4 + 1] = v.y; lds[r][c4 + 2] = v.z; lds[r][c4 + 3] = v.w;
    }
    __syncthreads();
    const int lane = tid & 63, wid = tid >> 6;
#pragma unroll
    for (int j = 0; j < 4; ++j) {
        int s = wid * 4 + j;
        int ig_l = s >> 3, ks_l = s & 7;
        int r = ig_l * 16 + (lane & 15);
        int c = ks_l * 32 + ((lane >> 4) << 3);
        uint2 o;
        o.x = pk4fp8(lds[r][c], lds[r][c + 1], lds[r][c + 2], lds[r][c + 3]);
        o.y = pk4fp8(lds[r][c + 4], lds[r][c + 5], lds[r][c + 6], lds[r][c + 7]);
        size_t ig = rt * 2 + ig_l, ks = (size_t)ct * 8 + ks_l;
        *(uint2*)(dst + ((ig * 48 + ks) * 64 + lane) * 8) = o;
    }
}

// ============================================================================
// conv_wq_fp8
// ============================================================================
__global__ __launch_bounds__(256)
void conv_wq_fp8(const float* __restrict__ wq, unsigned char* __restrict__ dst) {
    __shared__ float lds[32][258];
    const int tid = threadIdx.x;
    const int kt = blockIdx.x >> 5, nt = blockIdx.x & 31;
    const int k0 = kt * 32, n0 = nt * 256;
#pragma unroll
    for (int it = 0; it < 8; ++it) {
        int fid = it * 256 + tid;
        int k = fid >> 6, c4 = (fid & 63) << 2;
        float4 v = *(const float4*)(wq + (size_t)(k0 + k) * QN + n0 + c4);
        lds[k][c4] = v.x; lds[k][c4 + 1] = v.y; lds[k][c4 + 2] = v.z; lds[k][c4 + 3] = v.w;
    }
    __syncthreads();
    const int lane = tid & 63, wid = tid >> 6;
#pragma unroll
    for (int j = 0; j < 4; ++j) {
        int s = wid * 4 + j;
        int n_l = s * 16 + (lane & 15);
        int kb = (lane >> 4) << 3;
        uint2 o;
        o.x = pk4fp8(lds[kb][n_l], lds[kb + 1][n_l], lds[kb + 2][n_l], lds[kb + 3][n_l]);
        o.y = pk4fp8(lds[kb + 4][n_l], lds[kb + 5][n_l], lds[kb + 6][n_l], lds[kb + 7][n_l]);
        size_t ng = (size_t)nt * 16 + s;
        *(uint2*)(dst + ((ng * 48 + kt) * 64 + lane) * 8) = o;
    }
}

// ============================================================================
// conv_wkw
// ============================================================================
__global__ __launch_bounds__(256)
void conv_wkw(const float* __restrict__ wk, const float* __restrict__ wp,
              unsigned short* __restrict__ dst) {
    int gid = blockIdx.x * 4 + (threadIdx.x >> 6);
    int lane = threadIdx.x & 63;
    int ng = gid / 224, ks = gid - ng * 224;
    int col = ng * 16 + (lane & 15);
    int k = ks * 32 + ((lane >> 4) << 3);
    unsigned short o[8];
#pragma unroll
    for (int e = 0; e < 8; ++e) {
        float v = (col < 128) ? wk[(size_t)(k + e) * 128 + col]
                              : wp[(size_t)(k + e) * 64 + (col - 128)];
        o[e] = f2bf(v);
    }
    *(short8*)(dst + ((size_t)gid * 64 + lane) * 8) = *(short8*)o;
}

// ============================================================================
// kw_gemm_mfma
// ============================================================================
__global__ __launch_bounds__(256)
void kw_gemm_mfma(const unsigned short* __restrict__ hsfrag,
                  const unsigned short* __restrict__ wkwfrag,
                  float* __restrict__ part) {
    const int kz = blockIdx.x, mt = blockIdx.y;
    const int lane = threadIdx.x & 63, wid = threadIdx.x >> 6;
    const int ig = mt * 4 + wid;
    const f32x4 zed = {0.f, 0.f, 0.f, 0.f};
    f32x4 acc[12];
#pragma unroll
    for (int n = 0; n < 12; ++n) acc[n] = zed;
    for (int ks = kz * 56; ks < kz * 56 + 56; ++ks) {
        short8 a = *(const short8*)(hsfrag + (((size_t)ig * 224 + ks) * 64 + lane) * 8);
#pragma unroll
        for (int ng = 0; ng < 12; ++ng) {
            short8 b = *(const short8*)(wkwfrag + (((size_t)ng * 224 + ks) * 64 + lane) * 8);
            acc[ng] = MFMA16(a, b, acc[ng]);
        }
    }
    const int colc = lane & 15, rsub = (lane >> 4) << 2;
    float* pb = part + (size_t)kz * T_DIM * 192;
#pragma unroll
    for (int ng = 0; ng < 12; ++ng)
#pragma unroll
        for (int r = 0; r < 4; ++r) {
            int row = ig * 16 + rsub + r;
            pb[(size_t)row * 192 + ng * 16 + colc] = acc[ng][r];
        }
}

// ============================================================================
// reduce_w
// ============================================================================
__global__ __launch_bounds__(256)
void reduce_w(const float* __restrict__ part, float* __restrict__ wT) {
    __shared__ float lds[64][65];
    const int r0 = blockIdx.x * 64;
    const int tid = threadIdx.x;
#pragma unroll
    for (int it = 0; it < 16; ++it) {
        int fid = it * 256 + tid;
        int rl = fid >> 6, h = fid & 63;
        float s = 0.f;
#pragma unroll
        for (int z = 0; z < 4; ++z)
            s += part[((size_t)z * T_DIM + r0 + rl) * 192 + 128 + h];
        lds[rl][h] = s * WSCALE;
    }
    __syncthreads();
#pragma unroll
    for (int it = 0; it < 16; ++it) {
        int fid = it * 256 + tid;
        int h = fid >> 6, rl = fid & 63;
        wT[(size_t)h * T_DIM + r0 + rl] = lds[rl][h];
    }
}

// ============================================================================
// ln_rope_k
// ============================================================================
__global__ __launch_bounds__(256)
void ln_rope_k(const float* __restrict__ part, const float2* __restrict__ tab,
               const float* __restrict__ gamma, const float* __restrict__ beta,
               unsigned char* __restrict__ kfrag) {
    __shared__ float ln[4][128];
    const int tid = threadIdx.x;
    const int wr = tid >> 6, lane = tid & 63;
    const int row = blockIdx.x * 4 + wr;
    float2 v = make_float2(0.f, 0.f);
#pragma unroll
    for (int z = 0; z < 4; ++z) {
        float2 p = *(const float2*)(part + ((size_t)z * T_DIM + row) * 192 + lane * 2);
        v.x += p.x; v.y += p.y;
    }
    float s = v.x + v.y;
#pragma unroll
    for (int off = 1; off < 64; off <<= 1) s += __shfl_xor(s, off);
    float mu = s * (1.0f / 128.0f);
    float d0 = v.x - mu, d1 = v.y - mu;
    float s2 = d0 * d0 + d1 * d1;
#pragma unroll
    for (int off = 1; off < 64; off <<= 1) s2 += __shfl_xor(s2, off);
    float rstd = 1.0f / sqrtf(s2 * (1.0f / 128.0f) + 1e-6f);
    ln[wr][lane * 2]     = d0 * rstd * gamma[lane * 2]     + beta[lane * 2];
    ln[wr][lane * 2 + 1] = d1 * rstd * gamma[lane * 2 + 1] + beta[lane * 2 + 1];
    __syncthreads();
    int d = lane * 2;
    float o0, o1;
    float v0 = ln[wr][d], v1 = ln[wr][d + 1];
    if (d < 64) {
        int dd = d & 31;
        float2 c0 = tab[(size_t)row * 32 + dd];
        float2 c1 = tab[(size_t)row * 32 + dd + 1];
        if (d < 32) {
            o0 = v0 * c0.x - ln[wr][d + 32] * c0.y;
            o1 = v1 * c1.x - ln[wr][d + 33] * c1.y;
        } else {
            o0 = v0 * c0.x + ln[wr][d - 32] * c0.y;
            o1 = v1 * c1.x + ln[wr][d - 31] * c1.y;
        }
    } else { o0 = v0; o1 = v1; }
    int jg = row >> 4, ks = d >> 5, sub = d & 31;
    int lp = ((sub >> 3) << 4) + (row & 15);
    size_t bidx = (((size_t)jg * 4 + ks) * 64 + lp) * 8 + (sub & 7);
    unsigned pk = (unsigned)__builtin_amdgcn_cvt_pk_fp8_f32(o0, o1, 0, false);
    *(unsigned short*)(kfrag + bidx) = (unsigned short)(pk & 0xFFFFu);
}

// ============================================================================
// q_gemm_mfma: fp8 x fp8 -> qfrag fp8 A-frag
// ============================================================================
__global__ __launch_bounds__(256, 4)
void q_gemm_mfma(const unsigned char* __restrict__ qr8,
                 const unsigned char* __restrict__ wq8,
                 const float2* __restrict__ tab,
                 unsigned char* __restrict__ qfrag) {
    const int hw = blockIdx.x;
    const int orig = (hw & 7) * 256 + (hw >> 3);
    const int head = orig >> 5, mt = orig & 31;
    const int tid = threadIdx.x, lane = tid & 63, wid = tid >> 6;
    const int wm = wid >> 1, wn = wid & 1;
    const f32x4 zed = {0.f, 0.f, 0.f, 0.f};
    f32x4 acc[4][4];
#pragma unroll
    for (int m = 0; m < 4; m++)
#pragma unroll
        for (int n = 0; n < 4; n++) acc[m][n] = zed;

    const int ig0 = mt * 8 + wm * 4;
    const int ng0 = head * 8 + wn * 4;
    const unsigned char* ap = qr8 + ((size_t)ig0 * 48 * 64 + lane) * 8;
    const unsigned char* bp = wq8 + ((size_t)ng0 * 48 * 64 + lane) * 8;
    for (int ks = 0; ks < 48; ++ks) {
        long a[4], b[4];
#pragma unroll
        for (int m = 0; m < 4; m++)
            a[m] = *(const long*)(ap + ((size_t)m * 48 + ks) * 512);
#pragma unroll
        for (int n = 0; n < 4; n++)
            b[n] = *(const long*)(bp + ((size_t)n * 48 + ks) * 512);
#pragma unroll
        for (int m = 0; m < 4; m++)
#pragma unroll
            for (int n = 0; n < 4; n++)
                acc[m][n] = MFMA8(a[m], b[n], acc[m][n]);
    }
    const int colc = lane & 15;
    const int rsub = (lane >> 4) << 2;
#pragma unroll
    for (int m = 0; m < 4; m++) {
#pragma unroll
        for (int r = 0; r < 4; r++) {
            int row = mt * 128 + wm * 64 + m * 16 + rsub + r;
            int rl = rsub + r;
            size_t base = ((size_t)(row >> 4) * 64 + head) * 4;
            if (wn == 0) {
#pragma unroll
                for (int n2 = 0; n2 < 2; n2++) {
                    int dd = n2 * 16 + colc;
                    float2 cs = tab[(size_t)row * 32 + dd];
                    float x1 = acc[m][n2][r], x2 = acc[m][n2 + 2][r];
                    float olo = x1 * cs.x - x2 * cs.y;
                    float ohi = x2 * cs.x + x1 * cs.y;
                    int lp = ((dd >> 3) << 4) + rl;
                    qfrag[((base + 0) * 64 + lp) * 8 + (dd & 7)] = f2fp8(olo);
                    qfrag[((base + 1) * 64 + lp) * 8 + (dd & 7)] = f2fp8(ohi);
                }
            } else {
#pragma unroll
                for (int n = 0; n < 4; n++) {
                    int d = 64 + n * 16 + colc;
                    int ks2 = d >> 5, sub = d & 31;
                    int lp = ((sub >> 3) << 4) + rl;
                    qfrag[((base + ks2) * 64 + lp) * 8 + (sub & 7)] = f2fp8(acc[m][n][r]);
                }
            }
        }
    }
}

// ============================================================================
// scores_fill
// ============================================================================
__global__ __launch_bounds__(256)
void scores_fill(float* __restrict__ S) {
    const int bx = blockIdx.x, by = blockIdx.y;
    if (bx <= by) return;
    const int tid = threadIdx.x;
    float4 mv = make_float4(MASK_VAL, MASK_VAL, MASK_VAL, MASK_VAL);
#pragma unroll
    for (int l = 0; l < 16; l++) {
        int idx = l * 256 + tid;
        int r = idx >> 5, cg = idx & 31;
        *(float4*)(S + (size_t)(by * 128 + r) * T_DIM + bx * 128 + cg * 4) = mv;
    }
}

// ============================================================================
// scores_mfma v6: barrier-free + register double-buffered Q across h.
// The h-loop is unrolled by 2 with two named 16-frag buffers (static
// indexing, no scratch): load h+1 while computing h -> L2 latency fully
// hidden under the ~560cyc MFMA+VALU phase. (Round-10 model: per-m vmcnt
// waits were eating ~4x the compute time.)
// ============================================================================
__global__ __launch_bounds__(256, 2)
void scores_mfma(const unsigned char* __restrict__ qfrag,
                 const unsigned char* __restrict__ kfrag,
                 const float* __restrict__ wT, float* __restrict__ S) {
    int bid = blockIdx.x;                        // 0..527
    int by = (int)((sqrtf(8.f * bid + 1.f) - 1.f) * 0.5f);
    while ((by + 1) * (by + 2) / 2 <= bid) ++by;
    while (by * (by + 1) / 2 > bid) --by;
    const int jt = bid - by * (by + 1) / 2;
    __shared__ float wlds[64][128];
    const int tid = threadIdx.x;
    const int lane = tid & 63, wid = tid >> 6;
    const int wm = wid >> 1, wn = wid & 1;
    const int i0 = by * 128, j0 = jt * 128;
    const f32x4 zed = {0.f, 0.f, 0.f, 0.f};
#pragma unroll
    for (int it = 0; it < 32; ++it) {
        int fid = it * 256 + tid;
        int hh = fid >> 7, rl = fid & 127;
        wlds[hh][rl] = wT[(size_t)hh * T_DIM + i0 + rl];
    }
    long kf[4][4];
#pragma unroll
    for (int n = 0; n < 4; ++n) {
        int jg = (j0 >> 4) + wn * 4 + n;
#pragma unroll
        for (int ks = 0; ks < 4; ++ks)
            kf[n][ks] = *(const long*)(kfrag + (((size_t)jg * 4 + ks) * 64 + lane) * 8);
    }
    __syncthreads();

    f32x4 acc[4][4];
#pragma unroll
    for (int m = 0; m < 4; m++)
#pragma unroll
        for (int n = 0; n < 4; n++) acc[m][n] = zed;

    const int rsub = (lane >> 4) << 2;
    const unsigned char* qb[4];
#pragma unroll
    for (int m = 0; m < 4; ++m) {
        int ig = by * 8 + wm * 4 + m;
        qb[m] = qfrag + (size_t)ig * 64 * 2048 + lane * 8;
    }

    long a0[16], a1[16];
    auto loadQ = [&](long* dst, int h) {
#pragma unroll
        for (int m = 0; m < 4; ++m)
#pragma unroll
            for (int ks = 0; ks < 4; ++ks)
                dst[m * 4 + ks] = *(const long*)(qb[m] + (size_t)h * 2048 + ks * 512);
    };
    auto computeQ = [&](const long* a, int h) {
#pragma unroll
        for (int m = 0; m < 4; ++m) {
            f32x4 s[4] = {zed, zed, zed, zed};
#pragma unroll
            for (int ks = 0; ks < 4; ++ks)
#pragma unroll
                for (int n = 0; n < 4; ++n)
                    s[n] = MFMA8(a[m * 4 + ks], kf[n][ks], s[n]);
            f32x4 wv = *(const f32x4*)&wlds[h][wm * 64 + m * 16 + rsub];
#pragma unroll
            for (int n = 0; n < 4; ++n)
#pragma unroll
                for (int rr = 0; rr < 4; ++rr)
                    acc[m][n][rr] += wv[rr] * fmaxf(s[n][rr], 0.0f);
        }
    };

    loadQ(a0, 0);
#pragma unroll 2
    for (int h = 0; h < NH; h += 2) {
        loadQ(a1, h + 1);          // prefetch h+1 while computing h
        computeQ(a0, h);
        if (h + 2 < NH) loadQ(a0, h + 2);
        computeQ(a1, h + 1);
    }

    const int colc = lane & 15;
#pragma unroll
    for (int m = 0; m < 4; m++) {
#pragma unroll
        for (int n = 0; n < 4; n++) {
            int col = j0 + wn * 64 + n * 16 + colc;
#pragma unroll
            for (int rr = 0; rr < 4; rr++) {
                int row = i0 + wm * 64 + m * 16 + rsub + rr;
                float v = acc[m][n][rr];
                if (col > row) v = MASK_VAL;
                S[(size_t)row * T_DIM + col] = v;
            }
        }
    }
}

// ============================================================================
// topk v4: hybrid register/shuffle/LDS bitonic (verified round 10).
// ============================================================================
__device__ __forceinline__ void ce(unsigned &x, unsigned &y, bool up) {
    unsigned lo = x < y ? x : y, hi = x < y ? y : x;
    x = up ? lo : hi; y = up ? hi : lo;
}
__device__ __forceinline__ unsigned cd(unsigned a, unsigned b, bool keep_lo) {
    unsigned lo = a < b ? a : b, hi = a < b ? b : a;
    return keep_lo ? lo : hi;
}

__global__ __launch_bounds__(1024)
void topk_kernel(const float* __restrict__ S, float* __restrict__ outIdx) {
    __shared__ unsigned lds[4096];
    const int bid = blockIdx.x;
    const int tid = threadIdx.x;

    unsigned q0, q1, q2, q3;
    int row; unsigned e0; unsigned* L;

    if (bid < 1024) {            // two short rows per block
        const int half = tid >> 9;
        row = bid * 2 + half;
        e0 = 4u * (tid & 511);
        L = &lds[half * 2048];
    } else {                     // one long row
        row = bid + 1024;
        e0 = 4u * tid;
        L = lds;
    }
    const unsigned N = (bid < 1024) ? 2048u : 4096u;

    {   // load + pack keys + stages k=2,4
        float4 f = *(const float4*)(S + (size_t)row * T_DIM + e0);
        const float* fp = &f.x;
        unsigned qq[4];
#pragma unroll
        for (int e = 0; e < 4; ++e) {
            unsigned u = __float_as_uint(fp[e]);
            u = (u & 0x80000000u) ? ~u : (u | 0x80000000u);
            qq[e] = ((~u) & 0xFFFFF000u) | (e0 + e);
        }
        q0 = qq[0]; q1 = qq[1]; q2 = qq[2]; q3 = qq[3];
        ce(q0, q1, true); ce(q2, q3, false);           // k=2
        bool up4 = (e0 & 4u) == 0;                     // k=4
        ce(q0, q2, up4); ce(q1, q3, up4);
        ce(q0, q1, up4); ce(q2, q3, up4);
    }

    for (unsigned k = 8; k <= 2048u; k <<= 1) {
        for (unsigned j = k >> 1; j >= 4u; j >>= 1) {
            bool kl = ((e0 & k) == 0) ^ ((e0 & j) != 0);
            if (j >= 256u) {
                __syncthreads();
                *(uint4*)&L[e0] = make_uint4(q0, q1, q2, q3);
                __syncthreads();
                uint4 p = *(uint4*)&L[e0 ^ j];
                q0 = cd(q0, p.x, kl); q1 = cd(q1, p.y, kl);
                q2 = cd(q2, p.z, kl); q3 = cd(q3, p.w, kl);
            } else {
                int m = (int)(j >> 2);
                q0 = cd(q0, (unsigned)__shfl_xor((int)q0, m), kl);
                q1 = cd(q1, (unsigned)__shfl_xor((int)q1, m), kl);
                q2 = cd(q2, (unsigned)__shfl_xor((int)q2, m), kl);
                q3 = cd(q3, (unsigned)__shfl_xor((int)q3, m), kl);
            }
        }
        bool up = ((e0 & k) == 0);                     // j=2,1 in regs
        ce(q0, q2, up); ce(q1, q3, up);
        ce(q0, q1, up); ce(q2, q3, up);
    }

    if (N == 4096u) {
        __syncthreads();
        *(uint4*)&lds[e0] = make_uint4(q0, q1, q2, q3);
        __syncthreads();
        const bool low = e0 < 2048u;
        if (low) {
            uint4 p = *(uint4*)&lds[e0 + 2048];
            q0 = q0 < p.x ? q0 : p.x; q1 = q1 < p.y ? q1 : p.y;
            q2 = q2 < p.z ? q2 : p.z; q3 = q3 < p.w ? q3 : p.w;
        }
        for (unsigned j = 1024; j >= 256u; j >>= 1) {
            __syncthreads();
            if (low) *(uint4*)&lds[e0] = make_uint4(q0, q1, q2, q3);
            __syncthreads();
            if (low) {
                uint4 p = *(uint4*)&lds[e0 ^ j];
                bool kl = (e0 & j) == 0;
                q0 = cd(q0, p.x, kl); q1 = cd(q1, p.y, kl);
                q2 = cd(q2, p.z, kl); q3 = cd(q3, p.w, kl);
            }
        }
        if (low) {
#pragma unroll
            for (unsigned j = 128; j >= 4u; j >>= 1) {
                bool kl = (e0 & j) == 0;
                int m = (int)(j >> 2);
                q0 = cd(q0, (unsigned)__shfl_xor((int)q0, m), kl);
                q1 = cd(q1, (unsigned)__shfl_xor((int)q1, m), kl);
                q2 = cd(q2, (unsigned)__shfl_xor((int)q2, m), kl);
                q3 = cd(q3, (unsigned)__shfl_xor((int)q3, m), kl);
            }
            ce(q0, q2, true); ce(q1, q3, true);
            ce(q0, q1, true); ce(q2, q3, true);
            float4 o = make_float4((float)(q0 & 0xFFFu), (float)(q1 & 0xFFFu),
                                   (float)(q2 & 0xFFFu), (float)(q3 & 0xFFFu));
            *(float4*)(outIdx + (size_t)row * TOPK_N + e0) = o;
        }
    } else {
        float4 o = make_float4((float)(q0 & 0xFFFu), (float)(q1 & 0xFFFu),
                               (float)(q2 & 0xFFFu), (float)(q3 & 0xFFFu));
        *(float4*)(outIdx + (size_t)row * TOPK_N + e0) = o;
    }
}

// ============================================================================
extern "C" void kernel_launch(void* const* d_in, const int* in_sizes, int n_in,
                              void* d_out, int out_size, void* d_ws, size_t ws_size,
                              hipStream_t stream) {
    const float* hs      = (const float*)d_in[0];
    const float* qr      = (const float*)d_in[1];
    const int*   pos     = (const int*)  d_in[2];
    const float* wq_b    = (const float*)d_in[3];
    const float* wk      = (const float*)d_in[4];
    const float* k_gamma = (const float*)d_in[5];
    const float* k_beta  = (const float*)d_in[6];
    const float* w_proj  = (const float*)d_in[7];

    float* out     = (float*)d_out;
    float* out_idx = out;
    float* S       = out + (size_t)T_DIM * TOPK_N;

    char* wsp = (char*)d_ws;
    unsigned char*  qfrag  = (unsigned char*)wsp;  wsp += (size_t)67108864;
    unsigned short* hsfrag = (unsigned short*)qfrag;  // alias: hs consumed before qfrag written
    unsigned char*  qrfrag = (unsigned char*)wsp;  wsp += (size_t)12582912;
    unsigned char*  wqfrag = (unsigned char*)wsp;  wsp += (size_t)25165824;
    unsigned short* wkwfrag= (unsigned short*)wsp; wsp += (size_t)2752512;
    float*          part   = (float*)wsp;          wsp += (size_t)12582912;
    float*          wT     = (float*)wsp;          wsp += (size_t)1048576;
    unsigned char*  kfrag  = (unsigned char*)wsp;  wsp += (size_t)1048576;
    float2*         tab    = (float2*)wsp;         wsp += (size_t)1048576;

    rope_tab_kernel<<<512, 256, 0, stream>>>(pos, tab);
    conv_afrag <<<3584, 256, 0, stream>>>(hs, hsfrag, HSZ, 224, 28);
    conv_wkw   <<<672,  256, 0, stream>>>(wk, w_proj, wkwfrag);
    kw_gemm_mfma<<<dim3(4, 64), 256, 0, stream>>>(hsfrag, wkwfrag, part);
    reduce_w   <<<64,   256, 0, stream>>>(part, wT);
    ln_rope_k  <<<T_DIM / 4, 256, 0, stream>>>(part, tab, k_gamma, k_beta, kfrag);
    conv_qr_fp8<<<768,  256, 0, stream>>>(qr, qrfrag);
    conv_wq_fp8<<<1536, 256, 0, stream>>>(wq_b, wqfrag);
    q_gemm_mfma<<<2048, 256, 0, stream>>>(qrfrag, wqfrag, tab, qfrag);
    scores_fill<<<dim3(32, 32), 256, 0, stream>>>(S);
    scores_mfma<<<528, 256, 0, stream>>>(qfrag, kfrag, wT, S);
    topk_kernel<<<3072, 1024, 0, stream>>>(S, out_idx);
}

// Round 12
// 624.949 us; speedup vs baseline: 1.6356x; 1.6356x over previous
//
#include <hip/hip_runtime.h>
#include <hip/hip_bf16.h>
#include <math.h>

#define T_DIM 4096
#define HSZ   7168
#define QLR_K 1536
#define NH    64
#define HD    128
#define QN    (NH*HD)   // 8192
#define TOPK_N 2048
#define MASK_VAL (-3.0e38f)
// 0.125 (w_proj scale) * 128^-0.5 (q scale, folded out of fp8 q for precision)
#define WSCALE 0.011048543456039806f

using short8 = __attribute__((ext_vector_type(8))) short;   // 8 bf16 (4 VGPR)
using f32x4  = __attribute__((ext_vector_type(4))) float;

#define MFMA16(a,b,c) __builtin_amdgcn_mfma_f32_16x16x32_bf16(a,b,c,0,0,0)
#define MFMA8(a,b,c)  __builtin_amdgcn_mfma_f32_16x16x32_fp8_fp8(a,b,c,0,0,0)

__device__ __forceinline__ float rope_invf(int d) {
    return (float)(1.0 / pow(10000.0, (double)d / 32.0));
}
__device__ __forceinline__ unsigned short f2bf(float f) {
    unsigned u = __float_as_uint(f);
    return (unsigned short)((u + 0x7FFFu + ((u >> 16) & 1u)) >> 16);
}
// HW fp8 e4m3 conversion (v_cvt_pk_fp8_f32, gfx940+)
__device__ __forceinline__ unsigned char f2fp8(float x) {
    return (unsigned char)(__builtin_amdgcn_cvt_pk_fp8_f32(x, x, 0, false) & 0xFF);
}
__device__ __forceinline__ unsigned pk4fp8(float a, float b, float c, float d) {
    unsigned w = (unsigned)__builtin_amdgcn_cvt_pk_fp8_f32(a, b, 0, false);
    return (unsigned)__builtin_amdgcn_cvt_pk_fp8_f32(c, d, (int)w, true);
}

// ============================================================================
// rope_tab
// ============================================================================
__global__ __launch_bounds__(256)
void rope_tab_kernel(const int* __restrict__ positions, float2* __restrict__ tab) {
    int idx = blockIdx.x * 256 + threadIdx.x;
    int t = idx >> 5, dd = idx & 31;
    float p = (float)positions[t];
    float ang = p * rope_invf(dd);
    float s, c; sincosf(ang, &s, &c);
    tab[idx] = make_float2(c, s);
}

// ============================================================================
// conv_afrag (bf16, for hs -> kw path)
// ============================================================================
__global__ __launch_bounds__(256)
void conv_afrag(const float* __restrict__ src, unsigned short* __restrict__ dst,
                int C, int KS, int ctiles) {
    __shared__ float lds[32][258];
    const int tid = threadIdx.x;
    const int rt = blockIdx.x / ctiles, ct = blockIdx.x - rt * ctiles;
    const int r0 = rt * 32, c0 = ct * 256;
#pragma unroll
    for (int it = 0; it < 8; ++it) {
        int fid = it * 256 + tid;
        int r = fid >> 6, c4 = (fid & 63) << 2;
        float4 v = *(const float4*)(src + (size_t)(r0 + r) * C + c0 + c4);
        lds[r][c4] = v.x; lds[r][c4 + 1] = v.y; lds[r][c4 + 2] = v.z; lds[r][c4 + 3] = v.w;
    }
    __syncthreads();
    const int lane = tid & 63, wid = tid >> 6;
#pragma unroll
    for (int j = 0; j < 4; ++j) {
        int s = wid * 4 + j;
        int ig_l = s >> 3, ks_l = s & 7;
        int r = ig_l * 16 + (lane & 15);
        int c = ks_l * 32 + ((lane >> 4) << 3);
        unsigned short o[8];
#pragma unroll
        for (int e = 0; e < 8; ++e) o[e] = f2bf(lds[r][c + e]);
        size_t ig = rt * 2 + ig_l, ks = (size_t)ct * 8 + ks_l;
        *(short8*)(dst + ((ig * KS + ks) * 64 + lane) * 8) = *(short8*)o;
    }
}

// ============================================================================
// conv_qr_fp8
// ============================================================================
__global__ __launch_bounds__(256)
void conv_qr_fp8(const float* __restrict__ src, unsigned char* __restrict__ dst) {
    __shared__ float lds[32][258];
    const int tid = threadIdx.x;
    const int rt = blockIdx.x / 6, ct = blockIdx.x - rt * 6;
    const int r0 = rt * 32, c0 = ct * 256;
#pragma unroll
    for (int it = 0; it < 8; ++it) {
        int fid = it * 256 + tid;
        int r = fid >> 6, c4 = (fid & 63) << 2;
        float4 v = *(const float4*)(src + (size_t)(r0 + r) * QLR_K + c0 + c4);
        lds[r][c4] = v.x; lds[r][c4 + 1] = v.y; lds[r][c4 + 2] = v.z; lds[r][c4 + 3] = v.w;
    }
    __syncthreads();
    const int lane = tid & 63, wid = tid >> 6;
#pragma unroll
    for (int j = 0; j < 4; ++j) {
        int s = wid * 4 + j;
        int ig_l = s >> 3, ks_l = s & 7;
        int r = ig_l * 16 + (lane & 15);
        int c = ks_l * 32 + ((lane >> 4) << 3);
        uint2 o;
        o.x = pk4fp8(lds[r][c], lds[r][c + 1], lds[r][c + 2], lds[r][c + 3]);
        o.y = pk4fp8(lds[r][c + 4], lds[r][c + 5], lds[r][c + 6], lds[r][c + 7]);
        size_t ig = rt * 2 + ig_l, ks = (size_t)ct * 8 + ks_l;
        *(uint2*)(dst + ((ig * 48 + ks) * 64 + lane) * 8) = o;
    }
}

// ============================================================================
// conv_wq_fp8
// ============================================================================
__global__ __launch_bounds__(256)
void conv_wq_fp8(const float* __restrict__ wq, unsigned char* __restrict__ dst) {
    __shared__ float lds[32][258];
    const int tid = threadIdx.x;
    const int kt = blockIdx.x >> 5, nt = blockIdx.x & 31;
    const int k0 = kt * 32, n0 = nt * 256;
#pragma unroll
    for (int it = 0; it < 8; ++it) {
        int fid = it * 256 + tid;
        int k = fid >> 6, c4 = (fid & 63) << 2;
        float4 v = *(const float4*)(wq + (size_t)(k0 + k) * QN + n0 + c4);
        lds[k][c4] = v.x; lds[k][c4 + 1] = v.y; lds[k][c4 + 2] = v.z; lds[k][c4 + 3] = v.w;
    }
    __syncthreads();
    const int lane = tid & 63, wid = tid >> 6;
#pragma unroll
    for (int j = 0; j < 4; ++j) {
        int s = wid * 4 + j;
        int n_l = s * 16 + (lane & 15);
        int kb = (lane >> 4) << 3;
        uint2 o;
        o.x = pk4fp8(lds[kb][n_l], lds[kb + 1][n_l], lds[kb + 2][n_l], lds[kb + 3][n_l]);
        o.y = pk4fp8(lds[kb + 4][n_l], lds[kb + 5][n_l], lds[kb + 6][n_l], lds[kb + 7][n_l]);
        size_t ng = (size_t)nt * 16 + s;
        *(uint2*)(dst + ((ng * 48 + kt) * 64 + lane) * 8) = o;
    }
}

// ============================================================================
// conv_wkw
// ============================================================================
__global__ __launch_bounds__(256)
void conv_wkw(const float* __restrict__ wk, const float* __restrict__ wp,
              unsigned short* __restrict__ dst) {
    int gid = blockIdx.x * 4 + (threadIdx.x >> 6);
    int lane = threadIdx.x & 63;
    int ng = gid / 224, ks = gid - ng * 224;
    int col = ng * 16 + (lane & 15);
    int k = ks * 32 + ((lane >> 4) << 3);
    unsigned short o[8];
#pragma unroll
    for (int e = 0; e < 8; ++e) {
        float v = (col < 128) ? wk[(size_t)(k + e) * 128 + col]
                              : wp[(size_t)(k + e) * 64 + (col - 128)];
        o[e] = f2bf(v);
    }
    *(short8*)(dst + ((size_t)gid * 64 + lane) * 8) = *(short8*)o;
}

// ============================================================================
// kw_gemm_mfma
// ============================================================================
__global__ __launch_bounds__(256)
void kw_gemm_mfma(const unsigned short* __restrict__ hsfrag,
                  const unsigned short* __restrict__ wkwfrag,
                  float* __restrict__ part) {
    const int kz = blockIdx.x, mt = blockIdx.y;
    const int lane = threadIdx.x & 63, wid = threadIdx.x >> 6;
    const int ig = mt * 4 + wid;
    const f32x4 zed = {0.f, 0.f, 0.f, 0.f};
    f32x4 acc[12];
#pragma unroll
    for (int n = 0; n < 12; ++n) acc[n] = zed;
    for (int ks = kz * 56; ks < kz * 56 + 56; ++ks) {
        short8 a = *(const short8*)(hsfrag + (((size_t)ig * 224 + ks) * 64 + lane) * 8);
#pragma unroll
        for (int ng = 0; ng < 12; ++ng) {
            short8 b = *(const short8*)(wkwfrag + (((size_t)ng * 224 + ks) * 64 + lane) * 8);
            acc[ng] = MFMA16(a, b, acc[ng]);
        }
    }
    const int colc = lane & 15, rsub = (lane >> 4) << 2;
    float* pb = part + (size_t)kz * T_DIM * 192;
#pragma unroll
    for (int ng = 0; ng < 12; ++ng)
#pragma unroll
        for (int r = 0; r < 4; ++r) {
            int row = ig * 16 + rsub + r;
            pb[(size_t)row * 192 + ng * 16 + colc] = acc[ng][r];
        }
}

// ============================================================================
// reduce_w
// ============================================================================
__global__ __launch_bounds__(256)
void reduce_w(const float* __restrict__ part, float* __restrict__ wT) {
    __shared__ float lds[64][65];
    const int r0 = blockIdx.x * 64;
    const int tid = threadIdx.x;
#pragma unroll
    for (int it = 0; it < 16; ++it) {
        int fid = it * 256 + tid;
        int rl = fid >> 6, h = fid & 63;
        float s = 0.f;
#pragma unroll
        for (int z = 0; z < 4; ++z)
            s += part[((size_t)z * T_DIM + r0 + rl) * 192 + 128 + h];
        lds[rl][h] = s * WSCALE;
    }
    __syncthreads();
#pragma unroll
    for (int it = 0; it < 16; ++it) {
        int fid = it * 256 + tid;
        int h = fid >> 6, rl = fid & 63;
        wT[(size_t)h * T_DIM + r0 + rl] = lds[rl][h];
    }
}

// ============================================================================
// ln_rope_k
// ============================================================================
__global__ __launch_bounds__(256)
void ln_rope_k(const float* __restrict__ part, const float2* __restrict__ tab,
               const float* __restrict__ gamma, const float* __restrict__ beta,
               unsigned char* __restrict__ kfrag) {
    __shared__ float ln[4][128];
    const int tid = threadIdx.x;
    const int wr = tid >> 6, lane = tid & 63;
    const int row = blockIdx.x * 4 + wr;
    float2 v = make_float2(0.f, 0.f);
#pragma unroll
    for (int z = 0; z < 4; ++z) {
        float2 p = *(const float2*)(part + ((size_t)z * T_DIM + row) * 192 + lane * 2);
        v.x += p.x; v.y += p.y;
    }
    float s = v.x + v.y;
#pragma unroll
    for (int off = 1; off < 64; off <<= 1) s += __shfl_xor(s, off);
    float mu = s * (1.0f / 128.0f);
    float d0 = v.x - mu, d1 = v.y - mu;
    float s2 = d0 * d0 + d1 * d1;
#pragma unroll
    for (int off = 1; off < 64; off <<= 1) s2 += __shfl_xor(s2, off);
    float rstd = 1.0f / sqrtf(s2 * (1.0f / 128.0f) + 1e-6f);
    ln[wr][lane * 2]     = d0 * rstd * gamma[lane * 2]     + beta[lane * 2];
    ln[wr][lane * 2 + 1] = d1 * rstd * gamma[lane * 2 + 1] + beta[lane * 2 + 1];
    __syncthreads();
    int d = lane * 2;
    float o0, o1;
    float v0 = ln[wr][d], v1 = ln[wr][d + 1];
    if (d < 64) {
        int dd = d & 31;
        float2 c0 = tab[(size_t)row * 32 + dd];
        float2 c1 = tab[(size_t)row * 32 + dd + 1];
        if (d < 32) {
            o0 = v0 * c0.x - ln[wr][d + 32] * c0.y;
            o1 = v1 * c1.x - ln[wr][d + 33] * c1.y;
        } else {
            o0 = v0 * c0.x + ln[wr][d - 32] * c0.y;
            o1 = v1 * c1.x + ln[wr][d - 31] * c1.y;
        }
    } else { o0 = v0; o1 = v1; }
    int jg = row >> 4, ks = d >> 5, sub = d & 31;
    int lp = ((sub >> 3) << 4) + (row & 15);
    size_t bidx = (((size_t)jg * 4 + ks) * 64 + lp) * 8 + (sub & 7);
    unsigned pk = (unsigned)__builtin_amdgcn_cvt_pk_fp8_f32(o0, o1, 0, false);
    *(unsigned short*)(kfrag + bidx) = (unsigned short)(pk & 0xFFFFu);
}

// ============================================================================
// q_gemm_mfma: fp8 x fp8 -> qfrag fp8 A-frag
// ============================================================================
__global__ __launch_bounds__(256, 4)
void q_gemm_mfma(const unsigned char* __restrict__ qr8,
                 const unsigned char* __restrict__ wq8,
                 const float2* __restrict__ tab,
                 unsigned char* __restrict__ qfrag) {
    const int hw = blockIdx.x;
    const int orig = (hw & 7) * 256 + (hw >> 3);
    const int head = orig >> 5, mt = orig & 31;
    const int tid = threadIdx.x, lane = tid & 63, wid = tid >> 6;
    const int wm = wid >> 1, wn = wid & 1;
    const f32x4 zed = {0.f, 0.f, 0.f, 0.f};
    f32x4 acc[4][4];
#pragma unroll
    for (int m = 0; m < 4; m++)
#pragma unroll
        for (int n = 0; n < 4; n++) acc[m][n] = zed;

    const int ig0 = mt * 8 + wm * 4;
    const int ng0 = head * 8 + wn * 4;
    const unsigned char* ap = qr8 + ((size_t)ig0 * 48 * 64 + lane) * 8;
    const unsigned char* bp = wq8 + ((size_t)ng0 * 48 * 64 + lane) * 8;
    for (int ks = 0; ks < 48; ++ks) {
        long a[4], b[4];
#pragma unroll
        for (int m = 0; m < 4; m++)
            a[m] = *(const long*)(ap + ((size_t)m * 48 + ks) * 512);
#pragma unroll
        for (int n = 0; n < 4; n++)
            b[n] = *(const long*)(bp + ((size_t)n * 48 + ks) * 512);
#pragma unroll
        for (int m = 0; m < 4; m++)
#pragma unroll
            for (int n = 0; n < 4; n++)
                acc[m][n] = MFMA8(a[m], b[n], acc[m][n]);
    }
    const int colc = lane & 15;
    const int rsub = (lane >> 4) << 2;
#pragma unroll
    for (int m = 0; m < 4; m++) {
#pragma unroll
        for (int r = 0; r < 4; r++) {
            int row = mt * 128 + wm * 64 + m * 16 + rsub + r;
            int rl = rsub + r;
            size_t base = ((size_t)(row >> 4) * 64 + head) * 4;
            if (wn == 0) {
#pragma unroll
                for (int n2 = 0; n2 < 2; n2++) {
                    int dd = n2 * 16 + colc;
                    float2 cs = tab[(size_t)row * 32 + dd];
                    float x1 = acc[m][n2][r], x2 = acc[m][n2 + 2][r];
                    float olo = x1 * cs.x - x2 * cs.y;
                    float ohi = x2 * cs.x + x1 * cs.y;
                    int lp = ((dd >> 3) << 4) + rl;
                    qfrag[((base + 0) * 64 + lp) * 8 + (dd & 7)] = f2fp8(olo);
                    qfrag[((base + 1) * 64 + lp) * 8 + (dd & 7)] = f2fp8(ohi);
                }
            } else {
#pragma unroll
                for (int n = 0; n < 4; n++) {
                    int d = 64 + n * 16 + colc;
                    int ks2 = d >> 5, sub = d & 31;
                    int lp = ((sub >> 3) << 4) + rl;
                    qfrag[((base + ks2) * 64 + lp) * 8 + (sub & 7)] = f2fp8(acc[m][n][r]);
                }
            }
        }
    }
}

// ============================================================================
// scores_fill
// ============================================================================
__global__ __launch_bounds__(256)
void scores_fill(float* __restrict__ S) {
    const int bx = blockIdx.x, by = blockIdx.y;
    if (bx <= by) return;
    const int tid = threadIdx.x;
    float4 mv = make_float4(MASK_VAL, MASK_VAL, MASK_VAL, MASK_VAL);
#pragma unroll
    for (int l = 0; l < 16; l++) {
        int idx = l * 256 + tid;
        int r = idx >> 5, cg = idx & 31;
        *(float4*)(S + (size_t)(by * 128 + r) * T_DIM + bx * 128 + cg * 4) = mv;
    }
}

// ============================================================================
// scores_mfma v7: barrier-free + register double-buffer across h, expressed
// with textual macros on locally-scoped arrays (NO lambdas / pointer passing
// -- round 11's lambda form sent a0/a1 to scratch: WRITE_SIZE 33MB->942MB).
// All indices compile-time after unroll; verify via WRITE_SIZE ~33MB.
// ============================================================================
#define LOAD_H(A, hh)                                                          \
    _Pragma("unroll")                                                          \
    for (int m_ = 0; m_ < 4; ++m_) {                                           \
        _Pragma("unroll")                                                      \
        for (int ks_ = 0; ks_ < 4; ++ks_)                                      \
            A[m_ * 4 + ks_] =                                                  \
                *(const long*)(qb[m_] + (size_t)(hh) * 2048 + ks_ * 512);      \
    }

#define COMPUTE_H(A, hh)                                                       \
    _Pragma("unroll")                                                          \
    for (int m_ = 0; m_ < 4; ++m_) {                                           \
        f32x4 s0 = zed, s1 = zed, s2 = zed, s3 = zed;                          \
        _Pragma("unroll")                                                      \
        for (int ks_ = 0; ks_ < 4; ++ks_) {                                    \
            s0 = MFMA8(A[m_ * 4 + ks_], kf[0][ks_], s0);                       \
            s1 = MFMA8(A[m_ * 4 + ks_], kf[1][ks_], s1);                       \
            s2 = MFMA8(A[m_ * 4 + ks_], kf[2][ks_], s2);                       \
            s3 = MFMA8(A[m_ * 4 + ks_], kf[3][ks_], s3);                       \
        }                                                                      \
        f32x4 wv = *(const f32x4*)&wlds[hh][wm * 64 + m_ * 16 + rsub];         \
        _Pragma("unroll")                                                      \
        for (int rr_ = 0; rr_ < 4; ++rr_) {                                    \
            acc[m_][0][rr_] += wv[rr_] * fmaxf(s0[rr_], 0.0f);                 \
            acc[m_][1][rr_] += wv[rr_] * fmaxf(s1[rr_], 0.0f);                 \
            acc[m_][2][rr_] += wv[rr_] * fmaxf(s2[rr_], 0.0f);                 \
            acc[m_][3][rr_] += wv[rr_] * fmaxf(s3[rr_], 0.0f);                 \
        }                                                                      \
    }

__global__ __launch_bounds__(256, 2)
void scores_mfma(const unsigned char* __restrict__ qfrag,
                 const unsigned char* __restrict__ kfrag,
                 const float* __restrict__ wT, float* __restrict__ S) {
    int bid = blockIdx.x;                        // 0..527
    int by = (int)((sqrtf(8.f * bid + 1.f) - 1.f) * 0.5f);
    while ((by + 1) * (by + 2) / 2 <= bid) ++by;
    while (by * (by + 1) / 2 > bid) --by;
    const int jt = bid - by * (by + 1) / 2;
    __shared__ float wlds[64][128];
    const int tid = threadIdx.x;
    const int lane = tid & 63, wid = tid >> 6;
    const int wm = wid >> 1, wn = wid & 1;
    const int i0 = by * 128, j0 = jt * 128;
    const f32x4 zed = {0.f, 0.f, 0.f, 0.f};
#pragma unroll
    for (int it = 0; it < 32; ++it) {
        int fid = it * 256 + tid;
        int hh = fid >> 7, rl = fid & 127;
        wlds[hh][rl] = wT[(size_t)hh * T_DIM + i0 + rl];
    }
    long kf[4][4];
#pragma unroll
    for (int n = 0; n < 4; ++n) {
        int jg = (j0 >> 4) + wn * 4 + n;
#pragma unroll
        for (int ks = 0; ks < 4; ++ks)
            kf[n][ks] = *(const long*)(kfrag + (((size_t)jg * 4 + ks) * 64 + lane) * 8);
    }
    __syncthreads();

    f32x4 acc[4][4];
#pragma unroll
    for (int m = 0; m < 4; m++)
#pragma unroll
        for (int n = 0; n < 4; n++) acc[m][n] = zed;

    const int rsub = (lane >> 4) << 2;
    const unsigned char* qb[4];
#pragma unroll
    for (int m = 0; m < 4; ++m) {
        int ig = by * 8 + wm * 4 + m;
        qb[m] = qfrag + (size_t)ig * 64 * 2048 + lane * 8;
    }

    long a0[16], a1[16];
    LOAD_H(a0, 0)
    for (int h = 0; h < NH; h += 2) {
        LOAD_H(a1, h + 1)          // prefetch h+1; waits land after COMPUTE(a0)
        COMPUTE_H(a0, h)
        if (h + 2 < NH) { LOAD_H(a0, h + 2) }
        COMPUTE_H(a1, h + 1)
    }

    const int colc = lane & 15;
#pragma unroll
    for (int m = 0; m < 4; m++) {
#pragma unroll
        for (int n = 0; n < 4; n++) {
            int col = j0 + wn * 64 + n * 16 + colc;
#pragma unroll
            for (int rr = 0; rr < 4; rr++) {
                int row = i0 + wm * 64 + m * 16 + rsub + rr;
                float v = acc[m][n][rr];
                if (col > row) v = MASK_VAL;
                S[(size_t)row * T_DIM + col] = v;
            }
        }
    }
}

// ============================================================================
// topk v4: hybrid register/shuffle/LDS bitonic (verified round 10).
// ============================================================================
__device__ __forceinline__ void ce(unsigned &x, unsigned &y, bool up) {
    unsigned lo = x < y ? x : y, hi = x < y ? y : x;
    x = up ? lo : hi; y = up ? hi : lo;
}
__device__ __forceinline__ unsigned cd(unsigned a, unsigned b, bool keep_lo) {
    unsigned lo = a < b ? a : b, hi = a < b ? b : a;
    return keep_lo ? lo : hi;
}

__global__ __launch_bounds__(1024)
void topk_kernel(const float* __restrict__ S, float* __restrict__ outIdx) {
    __shared__ unsigned lds[4096];
    const int bid = blockIdx.x;
    const int tid = threadIdx.x;

    unsigned q0, q1, q2, q3;
    int row; unsigned e0; unsigned* L;

    if (bid < 1024) {            // two short rows per block
        const int half = tid >> 9;
        row = bid * 2 + half;
        e0 = 4u * (tid & 511);
        L = &lds[half * 2048];
    } else {                     // one long row
        row = bid + 1024;
        e0 = 4u * tid;
        L = lds;
    }
    const unsigned N = (bid < 1024) ? 2048u : 4096u;

    {   // load + pack keys + stages k=2,4
        float4 f = *(const float4*)(S + (size_t)row * T_DIM + e0);
        const float* fp = &f.x;
        unsigned qq[4];
#pragma unroll
        for (int e = 0; e < 4; ++e) {
            unsigned u = __float_as_uint(fp[e]);
            u = (u & 0x80000000u) ? ~u : (u | 0x80000000u);
            qq[e] = ((~u) & 0xFFFFF000u) | (e0 + e);
        }
        q0 = qq[0]; q1 = qq[1]; q2 = qq[2]; q3 = qq[3];
        ce(q0, q1, true); ce(q2, q3, false);           // k=2
        bool up4 = (e0 & 4u) == 0;                     // k=4
        ce(q0, q2, up4); ce(q1, q3, up4);
        ce(q0, q1, up4); ce(q2, q3, up4);
    }

    for (unsigned k = 8; k <= 2048u; k <<= 1) {
        for (unsigned j = k >> 1; j >= 4u; j >>= 1) {
            bool kl = ((e0 & k) == 0) ^ ((e0 & j) != 0);
            if (j >= 256u) {
                __syncthreads();
                *(uint4*)&L[e0] = make_uint4(q0, q1, q2, q3);
                __syncthreads();
                uint4 p = *(uint4*)&L[e0 ^ j];
                q0 = cd(q0, p.x, kl); q1 = cd(q1, p.y, kl);
                q2 = cd(q2, p.z, kl); q3 = cd(q3, p.w, kl);
            } else {
                int m = (int)(j >> 2);
                q0 = cd(q0, (unsigned)__shfl_xor((int)q0, m), kl);
                q1 = cd(q1, (unsigned)__shfl_xor((int)q1, m), kl);
                q2 = cd(q2, (unsigned)__shfl_xor((int)q2, m), kl);
                q3 = cd(q3, (unsigned)__shfl_xor((int)q3, m), kl);
            }
        }
        bool up = ((e0 & k) == 0);                     // j=2,1 in regs
        ce(q0, q2, up); ce(q1, q3, up);
        ce(q0, q1, up); ce(q2, q3, up);
    }

    if (N == 4096u) {
        __syncthreads();
        *(uint4*)&lds[e0] = make_uint4(q0, q1, q2, q3);
        __syncthreads();
        const bool low = e0 < 2048u;
        if (low) {
            uint4 p = *(uint4*)&lds[e0 + 2048];
            q0 = q0 < p.x ? q0 : p.x; q1 = q1 < p.y ? q1 : p.y;
            q2 = q2 < p.z ? q2 : p.z; q3 = q3 < p.w ? q3 : p.w;
        }
        for (unsigned j = 1024; j >= 256u; j >>= 1) {
            __syncthreads();
            if (low) *(uint4*)&lds[e0] = make_uint4(q0, q1, q2, q3);
            __syncthreads();
            if (low) {
                uint4 p = *(uint4*)&lds[e0 ^ j];
                bool kl = (e0 & j) == 0;
                q0 = cd(q0, p.x, kl); q1 = cd(q1, p.y, kl);
                q2 = cd(q2, p.z, kl); q3 = cd(q3, p.w, kl);
            }
        }
        if (low) {
#pragma unroll
            for (unsigned j = 128; j >= 4u; j >>= 1) {
                bool kl = (e0 & j) == 0;
                int m = (int)(j >> 2);
                q0 = cd(q0, (unsigned)__shfl_xor((int)q0, m), kl);
                q1 = cd(q1, (unsigned)__shfl_xor((int)q1, m), kl);
                q2 = cd(q2, (unsigned)__shfl_xor((int)q2, m), kl);
                q3 = cd(q3, (unsigned)__shfl_xor((int)q3, m), kl);
            }
            ce(q0, q2, true); ce(q1, q3, true);
            ce(q0, q1, true); ce(q2, q3, true);
            float4 o = make_float4((float)(q0 & 0xFFFu), (float)(q1 & 0xFFFu),
                                   (float)(q2 & 0xFFFu), (float)(q3 & 0xFFFu));
            *(float4*)(outIdx + (size_t)row * TOPK_N + e0) = o;
        }
    } else {
        float4 o = make_float4((float)(q0 & 0xFFFu), (float)(q1 & 0xFFFu),
                               (float)(q2 & 0xFFFu), (float)(q3 & 0xFFFu));
        *(float4*)(outIdx + (size_t)row * TOPK_N + e0) = o;
    }
}

// ============================================================================
extern "C" void kernel_launch(void* const* d_in, const int* in_sizes, int n_in,
                              void* d_out, int out_size, void* d_ws, size_t ws_size,
                              hipStream_t stream) {
    const float* hs      = (const float*)d_in[0];
    const float* qr      = (const float*)d_in[1];
    const int*   pos     = (const int*)  d_in[2];
    const float* wq_b    = (const float*)d_in[3];
    const float* wk      = (const float*)d_in[4];
    const float* k_gamma = (const float*)d_in[5];
    const float* k_beta  = (const float*)d_in[6];
    const float* w_proj  = (const float*)d_in[7];

    float* out     = (float*)d_out;
    float* out_idx = out;
    float* S       = out + (size_t)T_DIM * TOPK_N;

    char* wsp = (char*)d_ws;
    unsigned char*  qfrag  = (unsigned char*)wsp;  wsp += (size_t)67108864;
    unsigned short* hsfrag = (unsigned short*)qfrag;  // alias: hs consumed before qfrag written
    unsigned char*  qrfrag = (unsigned char*)wsp;  wsp += (size_t)12582912;
    unsigned char*  wqfrag = (unsigned char*)wsp;  wsp += (size_t)25165824;
    unsigned short* wkwfrag= (unsigned short*)wsp; wsp += (size_t)2752512;
    float*          part   = (float*)wsp;          wsp += (size_t)12582912;
    float*          wT     = (float*)wsp;          wsp += (size_t)1048576;
    unsigned char*  kfrag  = (unsigned char*)wsp;  wsp += (size_t)1048576;
    float2*         tab    = (float2*)wsp;         wsp += (size_t)1048576;

    rope_tab_kernel<<<512, 256, 0, stream>>>(pos, tab);
    conv_afrag <<<3584, 256, 0, stream>>>(hs, hsfrag, HSZ, 224, 28);
    conv_wkw   <<<672,  256, 0, stream>>>(wk, w_proj, wkwfrag);
    kw_gemm_mfma<<<dim3(4, 64), 256, 0, stream>>>(hsfrag, wkwfrag, part);
    reduce_w   <<<64,   256, 0, stream>>>(part, wT);
    ln_rope_k  <<<T_DIM / 4, 256, 0, stream>>>(part, tab, k_gamma, k_beta, kfrag);
    conv_qr_fp8<<<768,  256, 0, stream>>>(qr, qrfrag);
    conv_wq_fp8<<<1536, 256, 0, stream>>>(wq_b, wqfrag);
    q_gemm_mfma<<<2048, 256, 0, stream>>>(qrfrag, wqfrag, tab, qfrag);
    scores_fill<<<dim3(32, 32), 256, 0, stream>>>(S);
    scores_mfma<<<528, 256, 0, stream>>>(qfrag, kfrag, wT, S);
    topk_kernel<<<3072, 1024, 0, stream>>>(S, out_idx);
}

// Round 13
// 489.759 us; speedup vs baseline: 2.0871x; 1.2760x over previous
//
#include <hip/hip_runtime.h>
#include <hip/hip_bf16.h>
#include <math.h>

#define T_DIM 4096
#define HSZ   7168
#define QLR_K 1536
#define NH    64
#define HD    128
#define QN    (NH*HD)   // 8192
#define TOPK_N 2048
#define MASK_VAL (-3.0e38f)
// 0.125 (w_proj scale) * 128^-0.5 (q scale, folded out of fp8 q for precision)
#define WSCALE 0.011048543456039806f

using short8 = __attribute__((ext_vector_type(8))) short;   // 8 bf16 (4 VGPR)
using f32x4  = __attribute__((ext_vector_type(4))) float;

#define MFMA16(a,b,c) __builtin_amdgcn_mfma_f32_16x16x32_bf16(a,b,c,0,0,0)
#define MFMA8(a,b,c)  __builtin_amdgcn_mfma_f32_16x16x32_fp8_fp8(a,b,c,0,0,0)

__device__ __forceinline__ float rope_invf(int d) {
    return (float)(1.0 / pow(10000.0, (double)d / 32.0));
}
__device__ __forceinline__ unsigned short f2bf(float f) {
    unsigned u = __float_as_uint(f);
    return (unsigned short)((u + 0x7FFFu + ((u >> 16) & 1u)) >> 16);
}
// HW fp8 e4m3 conversion (v_cvt_pk_fp8_f32, gfx940+)
__device__ __forceinline__ unsigned char f2fp8(float x) {
    return (unsigned char)(__builtin_amdgcn_cvt_pk_fp8_f32(x, x, 0, false) & 0xFF);
}
__device__ __forceinline__ unsigned pk4fp8(float a, float b, float c, float d) {
    unsigned w = (unsigned)__builtin_amdgcn_cvt_pk_fp8_f32(a, b, 0, false);
    return (unsigned)__builtin_amdgcn_cvt_pk_fp8_f32(c, d, (int)w, true);
}

// ============================================================================
// rope_tab
// ============================================================================
__global__ __launch_bounds__(256)
void rope_tab_kernel(const int* __restrict__ positions, float2* __restrict__ tab) {
    int idx = blockIdx.x * 256 + threadIdx.x;
    int t = idx >> 5, dd = idx & 31;
    float p = (float)positions[t];
    float ang = p * rope_invf(dd);
    float s, c; sincosf(ang, &s, &c);
    tab[idx] = make_float2(c, s);
}

// ============================================================================
// conv_afrag (bf16, for hs -> kw path)
// ============================================================================
__global__ __launch_bounds__(256)
void conv_afrag(const float* __restrict__ src, unsigned short* __restrict__ dst,
                int C, int KS, int ctiles) {
    __shared__ float lds[32][258];
    const int tid = threadIdx.x;
    const int rt = blockIdx.x / ctiles, ct = blockIdx.x - rt * ctiles;
    const int r0 = rt * 32, c0 = ct * 256;
#pragma unroll
    for (int it = 0; it < 8; ++it) {
        int fid = it * 256 + tid;
        int r = fid >> 6, c4 = (fid & 63) << 2;
        float4 v = *(const float4*)(src + (size_t)(r0 + r) * C + c0 + c4);
        lds[r][c4] = v.x; lds[r][c4 + 1] = v.y; lds[r][c4 + 2] = v.z; lds[r][c4 + 3] = v.w;
    }
    __syncthreads();
    const int lane = tid & 63, wid = tid >> 6;
#pragma unroll
    for (int j = 0; j < 4; ++j) {
        int s = wid * 4 + j;
        int ig_l = s >> 3, ks_l = s & 7;
        int r = ig_l * 16 + (lane & 15);
        int c = ks_l * 32 + ((lane >> 4) << 3);
        unsigned short o[8];
#pragma unroll
        for (int e = 0; e < 8; ++e) o[e] = f2bf(lds[r][c + e]);
        size_t ig = rt * 2 + ig_l, ks = (size_t)ct * 8 + ks_l;
        *(short8*)(dst + ((ig * KS + ks) * 64 + lane) * 8) = *(short8*)o;
    }
}

// ============================================================================
// conv_qr_fp8
// ============================================================================
__global__ __launch_bounds__(256)
void conv_qr_fp8(const float* __restrict__ src, unsigned char* __restrict__ dst) {
    __shared__ float lds[32][258];
    const int tid = threadIdx.x;
    const int rt = blockIdx.x / 6, ct = blockIdx.x - rt * 6;
    const int r0 = rt * 32, c0 = ct * 256;
#pragma unroll
    for (int it = 0; it < 8; ++it) {
        int fid = it * 256 + tid;
        int r = fid >> 6, c4 = (fid & 63) << 2;
        float4 v = *(const float4*)(src + (size_t)(r0 + r) * QLR_K + c0 + c4);
        lds[r][c4] = v.x; lds[r][c4 + 1] = v.y; lds[r][c4 + 2] = v.z; lds[r][c4 + 3] = v.w;
    }
    __syncthreads();
    const int lane = tid & 63, wid = tid >> 6;
#pragma unroll
    for (int j = 0; j < 4; ++j) {
        int s = wid * 4 + j;
        int ig_l = s >> 3, ks_l = s & 7;
        int r = ig_l * 16 + (lane & 15);
        int c = ks_l * 32 + ((lane >> 4) << 3);
        uint2 o;
        o.x = pk4fp8(lds[r][c], lds[r][c + 1], lds[r][c + 2], lds[r][c + 3]);
        o.y = pk4fp8(lds[r][c + 4], lds[r][c + 5], lds[r][c + 6], lds[r][c + 7]);
        size_t ig = rt * 2 + ig_l, ks = (size_t)ct * 8 + ks_l;
        *(uint2*)(dst + ((ig * 48 + ks) * 64 + lane) * 8) = o;
    }
}

// ============================================================================
// conv_wq_fp8
// ============================================================================
__global__ __launch_bounds__(256)
void conv_wq_fp8(const float* __restrict__ wq, unsigned char* __restrict__ dst) {
    __shared__ float lds[32][258];
    const int tid = threadIdx.x;
    const int kt = blockIdx.x >> 5, nt = blockIdx.x & 31;
    const int k0 = kt * 32, n0 = nt * 256;
#pragma unroll
    for (int it = 0; it < 8; ++it) {
        int fid = it * 256 + tid;
        int k = fid >> 6, c4 = (fid & 63) << 2;
        float4 v = *(const float4*)(wq + (size_t)(k0 + k) * QN + n0 + c4);
        lds[k][c4] = v.x; lds[k][c4 + 1] = v.y; lds[k][c4 + 2] = v.z; lds[k][c4 + 3] = v.w;
    }
    __syncthreads();
    const int lane = tid & 63, wid = tid >> 6;
#pragma unroll
    for (int j = 0; j < 4; ++j) {
        int s = wid * 4 + j;
        int n_l = s * 16 + (lane & 15);
        int kb = (lane >> 4) << 3;
        uint2 o;
        o.x = pk4fp8(lds[kb][n_l], lds[kb + 1][n_l], lds[kb + 2][n_l], lds[kb + 3][n_l]);
        o.y = pk4fp8(lds[kb + 4][n_l], lds[kb + 5][n_l], lds[kb + 6][n_l], lds[kb + 7][n_l]);
        size_t ng = (size_t)nt * 16 + s;
        *(uint2*)(dst + ((ng * 48 + kt) * 64 + lane) * 8) = o;
    }
}

// ============================================================================
// conv_wkw
// ============================================================================
__global__ __launch_bounds__(256)
void conv_wkw(const float* __restrict__ wk, const float* __restrict__ wp,
              unsigned short* __restrict__ dst) {
    int gid = blockIdx.x * 4 + (threadIdx.x >> 6);
    int lane = threadIdx.x & 63;
    int ng = gid / 224, ks = gid - ng * 224;
    int col = ng * 16 + (lane & 15);
    int k = ks * 32 + ((lane >> 4) << 3);
    unsigned short o[8];
#pragma unroll
    for (int e = 0; e < 8; ++e) {
        float v = (col < 128) ? wk[(size_t)(k + e) * 128 + col]
                              : wp[(size_t)(k + e) * 64 + (col - 128)];
        o[e] = f2bf(v);
    }
    *(short8*)(dst + ((size_t)gid * 64 + lane) * 8) = *(short8*)o;
}

// ============================================================================
// kw_gemm_mfma v2: grid (kz 4)x(ig 256) = 1024 blocks -> 4 waves/SIMD
// (round-12 kernel ran at 1 wave/SIMD: 173us at 2.5% MfmaUtil, pure
// latency-serialization). Each block: one 16-row ig; 4 waves split 12 ngs
// 3-each; a-load identical across waves (L1 broadcast). unroll 4 for ILP.
// ============================================================================
__global__ __launch_bounds__(256, 4)
void kw_gemm_mfma(const unsigned short* __restrict__ hsfrag,
                  const unsigned short* __restrict__ wkwfrag,
                  float* __restrict__ part) {
    const int kz = blockIdx.x >> 8;              // 0..3
    const int ig = blockIdx.x & 255;             // 0..255
    const int lane = threadIdx.x & 63, wid = threadIdx.x >> 6;
    const f32x4 zed = {0.f, 0.f, 0.f, 0.f};
    f32x4 acc[3];
#pragma unroll
    for (int j = 0; j < 3; ++j) acc[j] = zed;

    const unsigned short* ap = hsfrag + ((size_t)ig * 224 * 64 + lane) * 8;
    const unsigned short* bp = wkwfrag + ((size_t)(wid * 3) * 224 * 64 + lane) * 8;
#pragma unroll 4
    for (int ks = kz * 56; ks < kz * 56 + 56; ++ks) {
        short8 a = *(const short8*)(ap + (size_t)ks * 512);
        short8 b0 = *(const short8*)(bp + (size_t)ks * 512);
        short8 b1 = *(const short8*)(bp + (size_t)(224 * 64 * 8) + (size_t)ks * 512);
        short8 b2 = *(const short8*)(bp + (size_t)(2 * 224 * 64 * 8) + (size_t)ks * 512);
        acc[0] = MFMA16(a, b0, acc[0]);
        acc[1] = MFMA16(a, b1, acc[1]);
        acc[2] = MFMA16(a, b2, acc[2]);
    }
    const int colc = lane & 15, rsub = (lane >> 4) << 2;
    float* pb = part + (size_t)kz * T_DIM * 192;
#pragma unroll
    for (int j = 0; j < 3; ++j) {
        int ng = wid * 3 + j;
#pragma unroll
        for (int r = 0; r < 4; ++r) {
            int row = ig * 16 + rsub + r;
            pb[(size_t)row * 192 + ng * 16 + colc] = acc[j][r];
        }
    }
}

// ============================================================================
// reduce_w
// ============================================================================
__global__ __launch_bounds__(256)
void reduce_w(const float* __restrict__ part, float* __restrict__ wT) {
    __shared__ float lds[64][65];
    const int r0 = blockIdx.x * 64;
    const int tid = threadIdx.x;
#pragma unroll
    for (int it = 0; it < 16; ++it) {
        int fid = it * 256 + tid;
        int rl = fid >> 6, h = fid & 63;
        float s = 0.f;
#pragma unroll
        for (int z = 0; z < 4; ++z)
            s += part[((size_t)z * T_DIM + r0 + rl) * 192 + 128 + h];
        lds[rl][h] = s * WSCALE;
    }
    __syncthreads();
#pragma unroll
    for (int it = 0; it < 16; ++it) {
        int fid = it * 256 + tid;
        int h = fid >> 6, rl = fid & 63;
        wT[(size_t)h * T_DIM + r0 + rl] = lds[rl][h];
    }
}

// ============================================================================
// ln_rope_k
// ============================================================================
__global__ __launch_bounds__(256)
void ln_rope_k(const float* __restrict__ part, const float2* __restrict__ tab,
               const float* __restrict__ gamma, const float* __restrict__ beta,
               unsigned char* __restrict__ kfrag) {
    __shared__ float ln[4][128];
    const int tid = threadIdx.x;
    const int wr = tid >> 6, lane = tid & 63;
    const int row = blockIdx.x * 4 + wr;
    float2 v = make_float2(0.f, 0.f);
#pragma unroll
    for (int z = 0; z < 4; ++z) {
        float2 p = *(const float2*)(part + ((size_t)z * T_DIM + row) * 192 + lane * 2);
        v.x += p.x; v.y += p.y;
    }
    float s = v.x + v.y;
#pragma unroll
    for (int off = 1; off < 64; off <<= 1) s += __shfl_xor(s, off);
    float mu = s * (1.0f / 128.0f);
    float d0 = v.x - mu, d1 = v.y - mu;
    float s2 = d0 * d0 + d1 * d1;
#pragma unroll
    for (int off = 1; off < 64; off <<= 1) s2 += __shfl_xor(s2, off);
    float rstd = 1.0f / sqrtf(s2 * (1.0f / 128.0f) + 1e-6f);
    ln[wr][lane * 2]     = d0 * rstd * gamma[lane * 2]     + beta[lane * 2];
    ln[wr][lane * 2 + 1] = d1 * rstd * gamma[lane * 2 + 1] + beta[lane * 2 + 1];
    __syncthreads();
    int d = lane * 2;
    float o0, o1;
    float v0 = ln[wr][d], v1 = ln[wr][d + 1];
    if (d < 64) {
        int dd = d & 31;
        float2 c0 = tab[(size_t)row * 32 + dd];
        float2 c1 = tab[(size_t)row * 32 + dd + 1];
        if (d < 32) {
            o0 = v0 * c0.x - ln[wr][d + 32] * c0.y;
            o1 = v1 * c1.x - ln[wr][d + 33] * c1.y;
        } else {
            o0 = v0 * c0.x + ln[wr][d - 32] * c0.y;
            o1 = v1 * c1.x + ln[wr][d - 31] * c1.y;
        }
    } else { o0 = v0; o1 = v1; }
    int jg = row >> 4, ks = d >> 5, sub = d & 31;
    int lp = ((sub >> 3) << 4) + (row & 15);
    size_t bidx = (((size_t)jg * 4 + ks) * 64 + lp) * 8 + (sub & 7);
    unsigned pk = (unsigned)__builtin_amdgcn_cvt_pk_fp8_f32(o0, o1, 0, false);
    *(unsigned short*)(kfrag + bidx) = (unsigned short)(pk & 0xFFFFu);
}

// ============================================================================
// q_gemm_mfma: fp8 x fp8 -> qfrag fp8 A-frag
// ============================================================================
__global__ __launch_bounds__(256, 4)
void q_gemm_mfma(const unsigned char* __restrict__ qr8,
                 const unsigned char* __restrict__ wq8,
                 const float2* __restrict__ tab,
                 unsigned char* __restrict__ qfrag) {
    const int hw = blockIdx.x;
    const int orig = (hw & 7) * 256 + (hw >> 3);
    const int head = orig >> 5, mt = orig & 31;
    const int tid = threadIdx.x, lane = tid & 63, wid = tid >> 6;
    const int wm = wid >> 1, wn = wid & 1;
    const f32x4 zed = {0.f, 0.f, 0.f, 0.f};
    f32x4 acc[4][4];
#pragma unroll
    for (int m = 0; m < 4; m++)
#pragma unroll
        for (int n = 0; n < 4; n++) acc[m][n] = zed;

    const int ig0 = mt * 8 + wm * 4;
    const int ng0 = head * 8 + wn * 4;
    const unsigned char* ap = qr8 + ((size_t)ig0 * 48 * 64 + lane) * 8;
    const unsigned char* bp = wq8 + ((size_t)ng0 * 48 * 64 + lane) * 8;
    for (int ks = 0; ks < 48; ++ks) {
        long a[4], b[4];
#pragma unroll
        for (int m = 0; m < 4; m++)
            a[m] = *(const long*)(ap + ((size_t)m * 48 + ks) * 512);
#pragma unroll
        for (int n = 0; n < 4; n++)
            b[n] = *(const long*)(bp + ((size_t)n * 48 + ks) * 512);
#pragma unroll
        for (int m = 0; m < 4; m++)
#pragma unroll
            for (int n = 0; n < 4; n++)
                acc[m][n] = MFMA8(a[m], b[n], acc[m][n]);
    }
    const int colc = lane & 15;
    const int rsub = (lane >> 4) << 2;
#pragma unroll
    for (int m = 0; m < 4; m++) {
#pragma unroll
        for (int r = 0; r < 4; r++) {
            int row = mt * 128 + wm * 64 + m * 16 + rsub + r;
            int rl = rsub + r;
            size_t base = ((size_t)(row >> 4) * 64 + head) * 4;
            if (wn == 0) {
#pragma unroll
                for (int n2 = 0; n2 < 2; n2++) {
                    int dd = n2 * 16 + colc;
                    float2 cs = tab[(size_t)row * 32 + dd];
                    float x1 = acc[m][n2][r], x2 = acc[m][n2 + 2][r];
                    float olo = x1 * cs.x - x2 * cs.y;
                    float ohi = x2 * cs.x + x1 * cs.y;
                    int lp = ((dd >> 3) << 4) + rl;
                    qfrag[((base + 0) * 64 + lp) * 8 + (dd & 7)] = f2fp8(olo);
                    qfrag[((base + 1) * 64 + lp) * 8 + (dd & 7)] = f2fp8(ohi);
                }
            } else {
#pragma unroll
                for (int n = 0; n < 4; n++) {
                    int d = 64 + n * 16 + colc;
                    int ks2 = d >> 5, sub = d & 31;
                    int lp = ((sub >> 3) << 4) + rl;
                    qfrag[((base + ks2) * 64 + lp) * 8 + (sub & 7)] = f2fp8(acc[m][n][r]);
                }
            }
        }
    }
}

// ============================================================================
// scores_fill
// ============================================================================
__global__ __launch_bounds__(256)
void scores_fill(float* __restrict__ S) {
    const int bx = blockIdx.x, by = blockIdx.y;
    if (bx <= by) return;
    const int tid = threadIdx.x;
    float4 mv = make_float4(MASK_VAL, MASK_VAL, MASK_VAL, MASK_VAL);
#pragma unroll
    for (int l = 0; l < 16; l++) {
        int idx = l * 256 + tid;
        int r = idx >> 5, cg = idx & 31;
        *(float4*)(S + (size_t)(by * 128 + r) * T_DIM + bx * 128 + cg * 4) = mv;
    }
}

// ============================================================================
// scores_mfma v7: barrier-free + register double-buffer across h (macros on
// locally-scoped arrays; round 11's lambda form spilled to scratch).
// ============================================================================
#define LOAD_H(A, hh)                                                          \
    _Pragma("unroll")                                                          \
    for (int m_ = 0; m_ < 4; ++m_) {                                           \
        _Pragma("unroll")                                                      \
        for (int ks_ = 0; ks_ < 4; ++ks_)                                      \
            A[m_ * 4 + ks_] =                                                  \
                *(const long*)(qb[m_] + (size_t)(hh) * 2048 + ks_ * 512);      \
    }

#define COMPUTE_H(A, hh)                                                       \
    _Pragma("unroll")                                                          \
    for (int m_ = 0; m_ < 4; ++m_) {                                           \
        f32x4 s0 = zed, s1 = zed, s2 = zed, s3 = zed;                          \
        _Pragma("unroll")                                                      \
        for (int ks_ = 0; ks_ < 4; ++ks_) {                                    \
            s0 = MFMA8(A[m_ * 4 + ks_], kf[0][ks_], s0);                       \
            s1 = MFMA8(A[m_ * 4 + ks_], kf[1][ks_], s1);                       \
            s2 = MFMA8(A[m_ * 4 + ks_], kf[2][ks_], s2);                       \
            s3 = MFMA8(A[m_ * 4 + ks_], kf[3][ks_], s3);                       \
        }                                                                      \
        f32x4 wv = *(const f32x4*)&wlds[hh][wm * 64 + m_ * 16 + rsub];         \
        _Pragma("unroll")                                                      \
        for (int rr_ = 0; rr_ < 4; ++rr_) {                                    \
            acc[m_][0][rr_] += wv[rr_] * fmaxf(s0[rr_], 0.0f);                 \
            acc[m_][1][rr_] += wv[rr_] * fmaxf(s1[rr_], 0.0f);                 \
            acc[m_][2][rr_] += wv[rr_] * fmaxf(s2[rr_], 0.0f);                 \
            acc[m_][3][rr_] += wv[rr_] * fmaxf(s3[rr_], 0.0f);                 \
        }                                                                      \
    }

__global__ __launch_bounds__(256, 2)
void scores_mfma(const unsigned char* __restrict__ qfrag,
                 const unsigned char* __restrict__ kfrag,
                 const float* __restrict__ wT, float* __restrict__ S) {
    int bid = blockIdx.x;                        // 0..527
    int by = (int)((sqrtf(8.f * bid + 1.f) - 1.f) * 0.5f);
    while ((by + 1) * (by + 2) / 2 <= bid) ++by;
    while (by * (by + 1) / 2 > bid) --by;
    const int jt = bid - by * (by + 1) / 2;
    __shared__ float wlds[64][128];
    const int tid = threadIdx.x;
    const int lane = tid & 63, wid = tid >> 6;
    const int wm = wid >> 1, wn = wid & 1;
    const int i0 = by * 128, j0 = jt * 128;
    const f32x4 zed = {0.f, 0.f, 0.f, 0.f};
#pragma unroll
    for (int it = 0; it < 32; ++it) {
        int fid = it * 256 + tid;
        int hh = fid >> 7, rl = fid & 127;
        wlds[hh][rl] = wT[(size_t)hh * T_DIM + i0 + rl];
    }
    long kf[4][4];
#pragma unroll
    for (int n = 0; n < 4; ++n) {
        int jg = (j0 >> 4) + wn * 4 + n;
#pragma unroll
        for (int ks = 0; ks < 4; ++ks)
            kf[n][ks] = *(const long*)(kfrag + (((size_t)jg * 4 + ks) * 64 + lane) * 8);
    }
    __syncthreads();

    f32x4 acc[4][4];
#pragma unroll
    for (int m = 0; m < 4; m++)
#pragma unroll
        for (int n = 0; n < 4; n++) acc[m][n] = zed;

    const int rsub = (lane >> 4) << 2;
    const unsigned char* qb[4];
#pragma unroll
    for (int m = 0; m < 4; ++m) {
        int ig = by * 8 + wm * 4 + m;
        qb[m] = qfrag + (size_t)ig * 64 * 2048 + lane * 8;
    }

    long a0[16], a1[16];
    LOAD_H(a0, 0)
    for (int h = 0; h < NH; h += 2) {
        LOAD_H(a1, h + 1)          // prefetch h+1; waits land after COMPUTE(a0)
        COMPUTE_H(a0, h)
        if (h + 2 < NH) { LOAD_H(a0, h + 2) }
        COMPUTE_H(a1, h + 1)
    }

    const int colc = lane & 15;
#pragma unroll
    for (int m = 0; m < 4; m++) {
#pragma unroll
        for (int n = 0; n < 4; n++) {
            int col = j0 + wn * 64 + n * 16 + colc;
#pragma unroll
            for (int rr = 0; rr < 4; rr++) {
                int row = i0 + wm * 64 + m * 16 + rsub + rr;
                float v = acc[m][n][rr];
                if (col > row) v = MASK_VAL;
                S[(size_t)row * T_DIM + col] = v;
            }
        }
    }
}

// ============================================================================
// topk v4: hybrid register/shuffle/LDS bitonic (verified round 10).
// ============================================================================
__device__ __forceinline__ void ce(unsigned &x, unsigned &y, bool up) {
    unsigned lo = x < y ? x : y, hi = x < y ? y : x;
    x = up ? lo : hi; y = up ? hi : lo;
}
__device__ __forceinline__ unsigned cd(unsigned a, unsigned b, bool keep_lo) {
    unsigned lo = a < b ? a : b, hi = a < b ? b : a;
    return keep_lo ? lo : hi;
}

__global__ __launch_bounds__(1024)
void topk_kernel(const float* __restrict__ S, float* __restrict__ outIdx) {
    __shared__ unsigned lds[4096];
    const int bid = blockIdx.x;
    const int tid = threadIdx.x;

    unsigned q0, q1, q2, q3;
    int row; unsigned e0; unsigned* L;

    if (bid < 1024) {            // two short rows per block
        const int half = tid >> 9;
        row = bid * 2 + half;
        e0 = 4u * (tid & 511);
        L = &lds[half * 2048];
    } else {                     // one long row
        row = bid + 1024;
        e0 = 4u * tid;
        L = lds;
    }
    const unsigned N = (bid < 1024) ? 2048u : 4096u;

    {   // load + pack keys + stages k=2,4
        float4 f = *(const float4*)(S + (size_t)row * T_DIM + e0);
        const float* fp = &f.x;
        unsigned qq[4];
#pragma unroll
        for (int e = 0; e < 4; ++e) {
            unsigned u = __float_as_uint(fp[e]);
            u = (u & 0x80000000u) ? ~u : (u | 0x80000000u);
            qq[e] = ((~u) & 0xFFFFF000u) | (e0 + e);
        }
        q0 = qq[0]; q1 = qq[1]; q2 = qq[2]; q3 = qq[3];
        ce(q0, q1, true); ce(q2, q3, false);           // k=2
        bool up4 = (e0 & 4u) == 0;                     // k=4
        ce(q0, q2, up4); ce(q1, q3, up4);
        ce(q0, q1, up4); ce(q2, q3, up4);
    }

    for (unsigned k = 8; k <= 2048u; k <<= 1) {
        for (unsigned j = k >> 1; j >= 4u; j >>= 1) {
            bool kl = ((e0 & k) == 0) ^ ((e0 & j) != 0);
            if (j >= 256u) {
                __syncthreads();
                *(uint4*)&L[e0] = make_uint4(q0, q1, q2, q3);
                __syncthreads();
                uint4 p = *(uint4*)&L[e0 ^ j];
                q0 = cd(q0, p.x, kl); q1 = cd(q1, p.y, kl);
                q2 = cd(q2, p.z, kl); q3 = cd(q3, p.w, kl);
            } else {
                int m = (int)(j >> 2);
                q0 = cd(q0, (unsigned)__shfl_xor((int)q0, m), kl);
                q1 = cd(q1, (unsigned)__shfl_xor((int)q1, m), kl);
                q2 = cd(q2, (unsigned)__shfl_xor((int)q2, m), kl);
                q3 = cd(q3, (unsigned)__shfl_xor((int)q3, m), kl);
            }
        }
        bool up = ((e0 & k) == 0);                     // j=2,1 in regs
        ce(q0, q2, up); ce(q1, q3, up);
        ce(q0, q1, up); ce(q2, q3, up);
    }

    if (N == 4096u) {
        __syncthreads();
        *(uint4*)&lds[e0] = make_uint4(q0, q1, q2, q3);
        __syncthreads();
        const bool low = e0 < 2048u;
        if (low) {
            uint4 p = *(uint4*)&lds[e0 + 2048];
            q0 = q0 < p.x ? q0 : p.x; q1 = q1 < p.y ? q1 : p.y;
            q2 = q2 < p.z ? q2 : p.z; q3 = q3 < p.w ? q3 : p.w;
        }
        for (unsigned j = 1024; j >= 256u; j >>= 1) {
            __syncthreads();
            if (low) *(uint4*)&lds[e0] = make_uint4(q0, q1, q2, q3);
            __syncthreads();
            if (low) {
                uint4 p = *(uint4*)&lds[e0 ^ j];
                bool kl = (e0 & j) == 0;
                q0 = cd(q0, p.x, kl); q1 = cd(q1, p.y, kl);
                q2 = cd(q2, p.z, kl); q3 = cd(q3, p.w, kl);
            }
        }
        if (low) {
#pragma unroll
            for (unsigned j = 128; j >= 4u; j >>= 1) {
                bool kl = (e0 & j) == 0;
                int m = (int)(j >> 2);
                q0 = cd(q0, (unsigned)__shfl_xor((int)q0, m), kl);
                q1 = cd(q1, (unsigned)__shfl_xor((int)q1, m), kl);
                q2 = cd(q2, (unsigned)__shfl_xor((int)q2, m), kl);
                q3 = cd(q3, (unsigned)__shfl_xor((int)q3, m), kl);
            }
            ce(q0, q2, true); ce(q1, q3, true);
            ce(q0, q1, true); ce(q2, q3, true);
            float4 o = make_float4((float)(q0 & 0xFFFu), (float)(q1 & 0xFFFu),
                                   (float)(q2 & 0xFFFu), (float)(q3 & 0xFFFu));
            *(float4*)(outIdx + (size_t)row * TOPK_N + e0) = o;
        }
    } else {
        float4 o = make_float4((float)(q0 & 0xFFFu), (float)(q1 & 0xFFFu),
                               (float)(q2 & 0xFFFu), (float)(q3 & 0xFFFu));
        *(float4*)(outIdx + (size_t)row * TOPK_N + e0) = o;
    }
}

// ============================================================================
extern "C" void kernel_launch(void* const* d_in, const int* in_sizes, int n_in,
                              void* d_out, int out_size, void* d_ws, size_t ws_size,
                              hipStream_t stream) {
    const float* hs      = (const float*)d_in[0];
    const float* qr      = (const float*)d_in[1];
    const int*   pos     = (const int*)  d_in[2];
    const float* wq_b    = (const float*)d_in[3];
    const float* wk      = (const float*)d_in[4];
    const float* k_gamma = (const float*)d_in[5];
    const float* k_beta  = (const float*)d_in[6];
    const float* w_proj  = (const float*)d_in[7];

    float* out     = (float*)d_out;
    float* out_idx = out;
    float* S       = out + (size_t)T_DIM * TOPK_N;

    char* wsp = (char*)d_ws;
    unsigned char*  qfrag  = (unsigned char*)wsp;  wsp += (size_t)67108864;
    unsigned short* hsfrag = (unsigned short*)qfrag;  // alias: hs consumed before qfrag written
    unsigned char*  qrfrag = (unsigned char*)wsp;  wsp += (size_t)12582912;
    unsigned char*  wqfrag = (unsigned char*)wsp;  wsp += (size_t)25165824;
    unsigned short* wkwfrag= (unsigned short*)wsp; wsp += (size_t)2752512;
    float*          part   = (float*)wsp;          wsp += (size_t)12582912;
    float*          wT     = (float*)wsp;          wsp += (size_t)1048576;
    unsigned char*  kfrag  = (unsigned char*)wsp;  wsp += (size_t)1048576;
    float2*         tab    = (float2*)wsp;         wsp += (size_t)1048576;

    rope_tab_kernel<<<512, 256, 0, stream>>>(pos, tab);
    conv_afrag <<<3584, 256, 0, stream>>>(hs, hsfrag, HSZ, 224, 28);
    conv_wkw   <<<672,  256, 0, stream>>>(wk, w_proj, wkwfrag);
    kw_gemm_mfma<<<1024, 256, 0, stream>>>(hsfrag, wkwfrag, part);
    reduce_w   <<<64,   256, 0, stream>>>(part, wT);
    ln_rope_k  <<<T_DIM / 4, 256, 0, stream>>>(part, tab, k_gamma, k_beta, kfrag);
    conv_qr_fp8<<<768,  256, 0, stream>>>(qr, qrfrag);
    conv_wq_fp8<<<1536, 256, 0, stream>>>(wq_b, wqfrag);
    q_gemm_mfma<<<2048, 256, 0, stream>>>(qrfrag, wqfrag, tab, qfrag);
    scores_fill<<<dim3(32, 32), 256, 0, stream>>>(S);
    scores_mfma<<<528, 256, 0, stream>>>(qfrag, kfrag, wT, S);
    topk_kernel<<<3072, 1024, 0, stream>>>(S, out_idx);
}

// Round 14
// 470.732 us; speedup vs baseline: 2.1715x; 1.0404x over previous
//
#include <hip/hip_runtime.h>
#include <hip/hip_bf16.h>
#include <math.h>

#define T_DIM 4096
#define HSZ   7168
#define QLR_K 1536
#define NH    64
#define HD    128
#define QN    (NH*HD)   // 8192
#define TOPK_N 2048
#define MASK_VAL (-3.0e38f)
// 0.125 (w_proj scale) * 128^-0.5 (q scale, folded out of fp8 q for precision)
#define WSCALE 0.011048543456039806f

using short8 = __attribute__((ext_vector_type(8))) short;   // 8 bf16 (4 VGPR)
using f32x4  = __attribute__((ext_vector_type(4))) float;

#define MFMA16(a,b,c) __builtin_amdgcn_mfma_f32_16x16x32_bf16(a,b,c,0,0,0)
#define MFMA8(a,b,c)  __builtin_amdgcn_mfma_f32_16x16x32_fp8_fp8(a,b,c,0,0,0)

__device__ __forceinline__ float rope_invf(int d) {
    return (float)(1.0 / pow(10000.0, (double)d / 32.0));
}
__device__ __forceinline__ unsigned short f2bf(float f) {
    unsigned u = __float_as_uint(f);
    return (unsigned short)((u + 0x7FFFu + ((u >> 16) & 1u)) >> 16);
}
// HW fp8 e4m3 conversion (v_cvt_pk_fp8_f32, gfx940+)
__device__ __forceinline__ unsigned char f2fp8(float x) {
    return (unsigned char)(__builtin_amdgcn_cvt_pk_fp8_f32(x, x, 0, false) & 0xFF);
}
__device__ __forceinline__ unsigned pk4fp8(float a, float b, float c, float d) {
    unsigned w = (unsigned)__builtin_amdgcn_cvt_pk_fp8_f32(a, b, 0, false);
    return (unsigned)__builtin_amdgcn_cvt_pk_fp8_f32(c, d, (int)w, true);
}

// ============================================================================
// rope_tab
// ============================================================================
__global__ __launch_bounds__(256)
void rope_tab_kernel(const int* __restrict__ positions, float2* __restrict__ tab) {
    int idx = blockIdx.x * 256 + threadIdx.x;
    int t = idx >> 5, dd = idx & 31;
    float p = (float)positions[t];
    float ang = p * rope_invf(dd);
    float s, c; sincosf(ang, &s, &c);
    tab[idx] = make_float2(c, s);
}

// ============================================================================
// conv_afrag (bf16, for hs -> kw path)
// ============================================================================
__global__ __launch_bounds__(256)
void conv_afrag(const float* __restrict__ src, unsigned short* __restrict__ dst,
                int C, int KS, int ctiles) {
    __shared__ float lds[32][258];
    const int tid = threadIdx.x;
    const int rt = blockIdx.x / ctiles, ct = blockIdx.x - rt * ctiles;
    const int r0 = rt * 32, c0 = ct * 256;
#pragma unroll
    for (int it = 0; it < 8; ++it) {
        int fid = it * 256 + tid;
        int r = fid >> 6, c4 = (fid & 63) << 2;
        float4 v = *(const float4*)(src + (size_t)(r0 + r) * C + c0 + c4);
        lds[r][c4] = v.x; lds[r][c4 + 1] = v.y; lds[r][c4 + 2] = v.z; lds[r][c4 + 3] = v.w;
    }
    __syncthreads();
    const int lane = tid & 63, wid = tid >> 6;
#pragma unroll
    for (int j = 0; j < 4; ++j) {
        int s = wid * 4 + j;
        int ig_l = s >> 3, ks_l = s & 7;
        int r = ig_l * 16 + (lane & 15);
        int c = ks_l * 32 + ((lane >> 4) << 3);
        unsigned short o[8];
#pragma unroll
        for (int e = 0; e < 8; ++e) o[e] = f2bf(lds[r][c + e]);
        size_t ig = rt * 2 + ig_l, ks = (size_t)ct * 8 + ks_l;
        *(short8*)(dst + ((ig * KS + ks) * 64 + lane) * 8) = *(short8*)o;
    }
}

// ============================================================================
// conv_qr_fp8
// ============================================================================
__global__ __launch_bounds__(256)
void conv_qr_fp8(const float* __restrict__ src, unsigned char* __restrict__ dst) {
    __shared__ float lds[32][258];
    const int tid = threadIdx.x;
    const int rt = blockIdx.x / 6, ct = blockIdx.x - rt * 6;
    const int r0 = rt * 32, c0 = ct * 256;
#pragma unroll
    for (int it = 0; it < 8; ++it) {
        int fid = it * 256 + tid;
        int r = fid >> 6, c4 = (fid & 63) << 2;
        float4 v = *(const float4*)(src + (size_t)(r0 + r) * QLR_K + c0 + c4);
        lds[r][c4] = v.x; lds[r][c4 + 1] = v.y; lds[r][c4 + 2] = v.z; lds[r][c4 + 3] = v.w;
    }
    __syncthreads();
    const int lane = tid & 63, wid = tid >> 6;
#pragma unroll
    for (int j = 0; j < 4; ++j) {
        int s = wid * 4 + j;
        int ig_l = s >> 3, ks_l = s & 7;
        int r = ig_l * 16 + (lane & 15);
        int c = ks_l * 32 + ((lane >> 4) << 3);
        uint2 o;
        o.x = pk4fp8(lds[r][c], lds[r][c + 1], lds[r][c + 2], lds[r][c + 3]);
        o.y = pk4fp8(lds[r][c + 4], lds[r][c + 5], lds[r][c + 6], lds[r][c + 7]);
        size_t ig = rt * 2 + ig_l, ks = (size_t)ct * 8 + ks_l;
        *(uint2*)(dst + ((ig * 48 + ks) * 64 + lane) * 8) = o;
    }
}

// ============================================================================
// conv_wq_fp8
// ============================================================================
__global__ __launch_bounds__(256)
void conv_wq_fp8(const float* __restrict__ wq, unsigned char* __restrict__ dst) {
    __shared__ float lds[32][258];
    const int tid = threadIdx.x;
    const int kt = blockIdx.x >> 5, nt = blockIdx.x & 31;
    const int k0 = kt * 32, n0 = nt * 256;
#pragma unroll
    for (int it = 0; it < 8; ++it) {
        int fid = it * 256 + tid;
        int k = fid >> 6, c4 = (fid & 63) << 2;
        float4 v = *(const float4*)(wq + (size_t)(k0 + k) * QN + n0 + c4);
        lds[k][c4] = v.x; lds[k][c4 + 1] = v.y; lds[k][c4 + 2] = v.z; lds[k][c4 + 3] = v.w;
    }
    __syncthreads();
    const int lane = tid & 63, wid = tid >> 6;
#pragma unroll
    for (int j = 0; j < 4; ++j) {
        int s = wid * 4 + j;
        int n_l = s * 16 + (lane & 15);
        int kb = (lane >> 4) << 3;
        uint2 o;
        o.x = pk4fp8(lds[kb][n_l], lds[kb + 1][n_l], lds[kb + 2][n_l], lds[kb + 3][n_l]);
        o.y = pk4fp8(lds[kb + 4][n_l], lds[kb + 5][n_l], lds[kb + 6][n_l], lds[kb + 7][n_l]);
        size_t ng = (size_t)nt * 16 + s;
        *(uint2*)(dst + ((ng * 48 + kt) * 64 + lane) * 8) = o;
    }
}

// ============================================================================
// conv_wkw
// ============================================================================
__global__ __launch_bounds__(256)
void conv_wkw(const float* __restrict__ wk, const float* __restrict__ wp,
              unsigned short* __restrict__ dst) {
    int gid = blockIdx.x * 4 + (threadIdx.x >> 6);
    int lane = threadIdx.x & 63;
    int ng = gid / 224, ks = gid - ng * 224;
    int col = ng * 16 + (lane & 15);
    int k = ks * 32 + ((lane >> 4) << 3);
    unsigned short o[8];
#pragma unroll
    for (int e = 0; e < 8; ++e) {
        float v = (col < 128) ? wk[(size_t)(k + e) * 128 + col]
                              : wp[(size_t)(k + e) * 64 + (col - 128)];
        o[e] = f2bf(v);
    }
    *(short8*)(dst + ((size_t)gid * 64 + lane) * 8) = *(short8*)o;
}

// ============================================================================
// kw_gemm_mfma v2 (verified round 13)
// ============================================================================
__global__ __launch_bounds__(256, 4)
void kw_gemm_mfma(const unsigned short* __restrict__ hsfrag,
                  const unsigned short* __restrict__ wkwfrag,
                  float* __restrict__ part) {
    const int kz = blockIdx.x >> 8;              // 0..3
    const int ig = blockIdx.x & 255;             // 0..255
    const int lane = threadIdx.x & 63, wid = threadIdx.x >> 6;
    const f32x4 zed = {0.f, 0.f, 0.f, 0.f};
    f32x4 acc[3];
#pragma unroll
    for (int j = 0; j < 3; ++j) acc[j] = zed;

    const unsigned short* ap = hsfrag + ((size_t)ig * 224 * 64 + lane) * 8;
    const unsigned short* bp = wkwfrag + ((size_t)(wid * 3) * 224 * 64 + lane) * 8;
#pragma unroll 4
    for (int ks = kz * 56; ks < kz * 56 + 56; ++ks) {
        short8 a = *(const short8*)(ap + (size_t)ks * 512);
        short8 b0 = *(const short8*)(bp + (size_t)ks * 512);
        short8 b1 = *(const short8*)(bp + (size_t)(224 * 64 * 8) + (size_t)ks * 512);
        short8 b2 = *(const short8*)(bp + (size_t)(2 * 224 * 64 * 8) + (size_t)ks * 512);
        acc[0] = MFMA16(a, b0, acc[0]);
        acc[1] = MFMA16(a, b1, acc[1]);
        acc[2] = MFMA16(a, b2, acc[2]);
    }
    const int colc = lane & 15, rsub = (lane >> 4) << 2;
    float* pb = part + (size_t)kz * T_DIM * 192;
#pragma unroll
    for (int j = 0; j < 3; ++j) {
        int ng = wid * 3 + j;
#pragma unroll
        for (int r = 0; r < 4; ++r) {
            int row = ig * 16 + rsub + r;
            pb[(size_t)row * 192 + ng * 16 + colc] = acc[j][r];
        }
    }
}

// ============================================================================
// reduce_w
// ============================================================================
__global__ __launch_bounds__(256)
void reduce_w(const float* __restrict__ part, float* __restrict__ wT) {
    __shared__ float lds[64][65];
    const int r0 = blockIdx.x * 64;
    const int tid = threadIdx.x;
#pragma unroll
    for (int it = 0; it < 16; ++it) {
        int fid = it * 256 + tid;
        int rl = fid >> 6, h = fid & 63;
        float s = 0.f;
#pragma unroll
        for (int z = 0; z < 4; ++z)
            s += part[((size_t)z * T_DIM + r0 + rl) * 192 + 128 + h];
        lds[rl][h] = s * WSCALE;
    }
    __syncthreads();
#pragma unroll
    for (int it = 0; it < 16; ++it) {
        int fid = it * 256 + tid;
        int h = fid >> 6, rl = fid & 63;
        wT[(size_t)h * T_DIM + r0 + rl] = lds[rl][h];
    }
}

// ============================================================================
// ln_rope_k
// ============================================================================
__global__ __launch_bounds__(256)
void ln_rope_k(const float* __restrict__ part, const float2* __restrict__ tab,
               const float* __restrict__ gamma, const float* __restrict__ beta,
               unsigned char* __restrict__ kfrag) {
    __shared__ float ln[4][128];
    const int tid = threadIdx.x;
    const int wr = tid >> 6, lane = tid & 63;
    const int row = blockIdx.x * 4 + wr;
    float2 v = make_float2(0.f, 0.f);
#pragma unroll
    for (int z = 0; z < 4; ++z) {
        float2 p = *(const float2*)(part + ((size_t)z * T_DIM + row) * 192 + lane * 2);
        v.x += p.x; v.y += p.y;
    }
    float s = v.x + v.y;
#pragma unroll
    for (int off = 1; off < 64; off <<= 1) s += __shfl_xor(s, off);
    float mu = s * (1.0f / 128.0f);
    float d0 = v.x - mu, d1 = v.y - mu;
    float s2 = d0 * d0 + d1 * d1;
#pragma unroll
    for (int off = 1; off < 64; off <<= 1) s2 += __shfl_xor(s2, off);
    float rstd = 1.0f / sqrtf(s2 * (1.0f / 128.0f) + 1e-6f);
    ln[wr][lane * 2]     = d0 * rstd * gamma[lane * 2]     + beta[lane * 2];
    ln[wr][lane * 2 + 1] = d1 * rstd * gamma[lane * 2 + 1] + beta[lane * 2 + 1];
    __syncthreads();
    int d = lane * 2;
    float o0, o1;
    float v0 = ln[wr][d], v1 = ln[wr][d + 1];
    if (d < 64) {
        int dd = d & 31;
        float2 c0 = tab[(size_t)row * 32 + dd];
        float2 c1 = tab[(size_t)row * 32 + dd + 1];
        if (d < 32) {
            o0 = v0 * c0.x - ln[wr][d + 32] * c0.y;
            o1 = v1 * c1.x - ln[wr][d + 33] * c1.y;
        } else {
            o0 = v0 * c0.x + ln[wr][d - 32] * c0.y;
            o1 = v1 * c1.x + ln[wr][d - 31] * c1.y;
        }
    } else { o0 = v0; o1 = v1; }
    int jg = row >> 4, ks = d >> 5, sub = d & 31;
    int lp = ((sub >> 3) << 4) + (row & 15);
    size_t bidx = (((size_t)jg * 4 + ks) * 64 + lp) * 8 + (sub & 7);
    unsigned pk = (unsigned)__builtin_amdgcn_cvt_pk_fp8_f32(o0, o1, 0, false);
    *(unsigned short*)(kfrag + bidx) = (unsigned short)(pk & 0xFFFFu);
}

// ============================================================================
// q_gemm_mfma: fp8 x fp8 -> qfrag fp8 A-frag
// ============================================================================
__global__ __launch_bounds__(256, 4)
void q_gemm_mfma(const unsigned char* __restrict__ qr8,
                 const unsigned char* __restrict__ wq8,
                 const float2* __restrict__ tab,
                 unsigned char* __restrict__ qfrag) {
    const int hw = blockIdx.x;
    const int orig = (hw & 7) * 256 + (hw >> 3);
    const int head = orig >> 5, mt = orig & 31;
    const int tid = threadIdx.x, lane = tid & 63, wid = tid >> 6;
    const int wm = wid >> 1, wn = wid & 1;
    const f32x4 zed = {0.f, 0.f, 0.f, 0.f};
    f32x4 acc[4][4];
#pragma unroll
    for (int m = 0; m < 4; m++)
#pragma unroll
        for (int n = 0; n < 4; n++) acc[m][n] = zed;

    const int ig0 = mt * 8 + wm * 4;
    const int ng0 = head * 8 + wn * 4;
    const unsigned char* ap = qr8 + ((size_t)ig0 * 48 * 64 + lane) * 8;
    const unsigned char* bp = wq8 + ((size_t)ng0 * 48 * 64 + lane) * 8;
    for (int ks = 0; ks < 48; ++ks) {
        long a[4], b[4];
#pragma unroll
        for (int m = 0; m < 4; m++)
            a[m] = *(const long*)(ap + ((size_t)m * 48 + ks) * 512);
#pragma unroll
        for (int n = 0; n < 4; n++)
            b[n] = *(const long*)(bp + ((size_t)n * 48 + ks) * 512);
#pragma unroll
        for (int m = 0; m < 4; m++)
#pragma unroll
            for (int n = 0; n < 4; n++)
                acc[m][n] = MFMA8(a[m], b[n], acc[m][n]);
    }
    const int colc = lane & 15;
    const int rsub = (lane >> 4) << 2;
#pragma unroll
    for (int m = 0; m < 4; m++) {
#pragma unroll
        for (int r = 0; r < 4; r++) {
            int row = mt * 128 + wm * 64 + m * 16 + rsub + r;
            int rl = rsub + r;
            size_t base = ((size_t)(row >> 4) * 64 + head) * 4;
            if (wn == 0) {
#pragma unroll
                for (int n2 = 0; n2 < 2; n2++) {
                    int dd = n2 * 16 + colc;
                    float2 cs = tab[(size_t)row * 32 + dd];
                    float x1 = acc[m][n2][r], x2 = acc[m][n2 + 2][r];
                    float olo = x1 * cs.x - x2 * cs.y;
                    float ohi = x2 * cs.x + x1 * cs.y;
                    int lp = ((dd >> 3) << 4) + rl;
                    qfrag[((base + 0) * 64 + lp) * 8 + (dd & 7)] = f2fp8(olo);
                    qfrag[((base + 1) * 64 + lp) * 8 + (dd & 7)] = f2fp8(ohi);
                }
            } else {
#pragma unroll
                for (int n = 0; n < 4; n++) {
                    int d = 64 + n * 16 + colc;
                    int ks2 = d >> 5, sub = d & 31;
                    int lp = ((sub >> 3) << 4) + rl;
                    qfrag[((base + ks2) * 64 + lp) * 8 + (sub & 7)] = f2fp8(acc[m][n][r]);
                }
            }
        }
    }
}

// ============================================================================
// scores_mfma v8: 64x128 tiles, 1056 blocks (4.1/CU; round-13 was grid-bound
// at 2.06/CU, MfmaUtil 37%). 4 waves 2(wm ig-pairs) x 2(wn 64-col). Register
// Q double-buffer across h (macros, locally-scoped arrays). No forced
// min-waves: natural VGPR ~125 -> 4 waves/SIMD without spill risk.
// ============================================================================
#define LOAD_H(A, hh)                                                          \
    _Pragma("unroll")                                                          \
    for (int m_ = 0; m_ < 2; ++m_) {                                           \
        _Pragma("unroll")                                                      \
        for (int ks_ = 0; ks_ < 4; ++ks_)                                      \
            A[m_ * 4 + ks_] =                                                  \
                *(const long*)(qb[m_] + (size_t)(hh) * 2048 + ks_ * 512);      \
    }

#define COMPUTE_H(A, hh)                                                       \
    _Pragma("unroll")                                                          \
    for (int m_ = 0; m_ < 2; ++m_) {                                           \
        f32x4 s0 = zed, s1 = zed, s2 = zed, s3 = zed;                          \
        _Pragma("unroll")                                                      \
        for (int ks_ = 0; ks_ < 4; ++ks_) {                                    \
            s0 = MFMA8(A[m_ * 4 + ks_], kf[0][ks_], s0);                       \
            s1 = MFMA8(A[m_ * 4 + ks_], kf[1][ks_], s1);                       \
            s2 = MFMA8(A[m_ * 4 + ks_], kf[2][ks_], s2);                       \
            s3 = MFMA8(A[m_ * 4 + ks_], kf[3][ks_], s3);                       \
        }                                                                      \
        f32x4 wv = *(const f32x4*)&wlds[hh][wm * 32 + m_ * 16 + rsub];         \
        _Pragma("unroll")                                                      \
        for (int rr_ = 0; rr_ < 4; ++rr_) {                                    \
            acc[m_][0][rr_] += wv[rr_] * fmaxf(s0[rr_], 0.0f);                 \
            acc[m_][1][rr_] += wv[rr_] * fmaxf(s1[rr_], 0.0f);                 \
            acc[m_][2][rr_] += wv[rr_] * fmaxf(s2[rr_], 0.0f);                 \
            acc[m_][3][rr_] += wv[rr_] * fmaxf(s3[rr_], 0.0f);                 \
        }                                                                      \
    }

__global__ __launch_bounds__(256)
void scores_mfma(const unsigned char* __restrict__ qfrag,
                 const unsigned char* __restrict__ kfrag,
                 const float* __restrict__ wT, float* __restrict__ S) {
    const int bid = blockIdx.x;                  // 0..1055
    int u = (int)((sqrtf(4.f * bid + 1.f) - 1.f) * 0.5f);
    while ((u + 1) * (u + 2) <= bid) ++u;
    while (u * (u + 1) > bid) --u;
    int r_ = bid - u * (u + 1);                  // 0..2u+1
    const int byp = (r_ <= u) ? 2 * u : 2 * u + 1;
    const int jt  = (r_ <= u) ? r_ : r_ - (u + 1);
    __shared__ float wlds[64][64];
    const int tid = threadIdx.x;
    const int lane = tid & 63, wid = tid >> 6;
    const int wm = wid >> 1, wn = wid & 1;       // 2 x 2
    const int i0 = byp * 64, j0 = jt * 128;
    const f32x4 zed = {0.f, 0.f, 0.f, 0.f};
#pragma unroll
    for (int it = 0; it < 16; ++it) {
        int fid = it * 256 + tid;
        int hh = fid >> 6, rl = fid & 63;
        wlds[hh][rl] = wT[(size_t)hh * T_DIM + i0 + rl];
    }
    long kf[4][4];
#pragma unroll
    for (int n = 0; n < 4; ++n) {
        int jg = (j0 >> 4) + wn * 4 + n;
#pragma unroll
        for (int ks = 0; ks < 4; ++ks)
            kf[n][ks] = *(const long*)(kfrag + (((size_t)jg * 4 + ks) * 64 + lane) * 8);
    }
    __syncthreads();

    f32x4 acc[2][4];
#pragma unroll
    for (int m = 0; m < 2; m++)
#pragma unroll
        for (int n = 0; n < 4; n++) acc[m][n] = zed;

    const int rsub = (lane >> 4) << 2;
    const unsigned char* qb[2];
#pragma unroll
    for (int m = 0; m < 2; ++m) {
        int ig = byp * 4 + wm * 2 + m;
        qb[m] = qfrag + (size_t)ig * 64 * 2048 + lane * 8;
    }

    long a0[8], a1[8];
    LOAD_H(a0, 0)
    for (int h = 0; h < NH; h += 2) {
        LOAD_H(a1, h + 1)          // prefetch h+1; waits land after COMPUTE(a0)
        COMPUTE_H(a0, h)
        if (h + 2 < NH) { LOAD_H(a0, h + 2) }
        COMPUTE_H(a1, h + 1)
    }

    const int colc = lane & 15;
#pragma unroll
    for (int m = 0; m < 2; m++) {
#pragma unroll
        for (int n = 0; n < 4; n++) {
            int col = j0 + wn * 64 + n * 16 + colc;
#pragma unroll
            for (int rr = 0; rr < 4; rr++) {
                int row = i0 + wm * 32 + m * 16 + rsub + rr;
                float v = acc[m][n][rr];
                if (col > row) v = MASK_VAL;
                S[(size_t)row * T_DIM + col] = v;
            }
        }
    }
}

// ============================================================================
// topk v5: masked positions (p > row) synthesized as 0xFFFFF000|p keys --
// sorts after every real key (real <= 0xFF8xxxxx), ties ascending index,
// exactly matching ref's -inf behavior. scores_fill kernel deleted.
// ============================================================================
__device__ __forceinline__ void ce(unsigned &x, unsigned &y, bool up) {
    unsigned lo = x < y ? x : y, hi = x < y ? y : x;
    x = up ? lo : hi; y = up ? hi : lo;
}
__device__ __forceinline__ unsigned cd(unsigned a, unsigned b, bool keep_lo) {
    unsigned lo = a < b ? a : b, hi = a < b ? b : a;
    return keep_lo ? lo : hi;
}

__global__ __launch_bounds__(1024)
void topk_kernel(const float* __restrict__ S, float* __restrict__ outIdx) {
    __shared__ unsigned lds[4096];
    const int bid = blockIdx.x;
    const int tid = threadIdx.x;

    unsigned q0, q1, q2, q3;
    int row; unsigned e0; unsigned* L;

    if (bid < 1024) {            // two short rows per block
        const int half = tid >> 9;
        row = bid * 2 + half;
        e0 = 4u * (tid & 511);
        L = &lds[half * 2048];
    } else {                     // one long row
        row = bid + 1024;
        e0 = 4u * tid;
        L = lds;
    }
    const unsigned N = (bid < 1024) ? 2048u : 4096u;

    {   // load + pack keys (masked p>row synthesized) + stages k=2,4
        float4 f = *(const float4*)(S + (size_t)row * T_DIM + e0);
        const float* fp = &f.x;
        unsigned qq[4];
#pragma unroll
        for (int e = 0; e < 4; ++e) {
            unsigned p = e0 + e;
            unsigned u = __float_as_uint(fp[e]);
            u = (u & 0x80000000u) ? ~u : (u | 0x80000000u);
            unsigned key = ((~u) & 0xFFFFF000u) | p;
            qq[e] = ((int)p > row) ? (0xFFFFF000u | p) : key;
        }
        q0 = qq[0]; q1 = qq[1]; q2 = qq[2]; q3 = qq[3];
        ce(q0, q1, true); ce(q2, q3, false);           // k=2
        bool up4 = (e0 & 4u) == 0;                     // k=4
        ce(q0, q2, up4); ce(q1, q3, up4);
        ce(q0, q1, up4); ce(q2, q3, up4);
    }

    for (unsigned k = 8; k <= 2048u; k <<= 1) {
        for (unsigned j = k >> 1; j >= 4u; j >>= 1) {
            bool kl = ((e0 & k) == 0) ^ ((e0 & j) != 0);
            if (j >= 256u) {
                __syncthreads();
                *(uint4*)&L[e0] = make_uint4(q0, q1, q2, q3);
                __syncthreads();
                uint4 p = *(uint4*)&L[e0 ^ j];
                q0 = cd(q0, p.x, kl); q1 = cd(q1, p.y, kl);
                q2 = cd(q2, p.z, kl); q3 = cd(q3, p.w, kl);
            } else {
                int m = (int)(j >> 2);
                q0 = cd(q0, (unsigned)__shfl_xor((int)q0, m), kl);
                q1 = cd(q1, (unsigned)__shfl_xor((int)q1, m), kl);
                q2 = cd(q2, (unsigned)__shfl_xor((int)q2, m), kl);
                q3 = cd(q3, (unsigned)__shfl_xor((int)q3, m), kl);
            }
        }
        bool up = ((e0 & k) == 0);                     // j=2,1 in regs
        ce(q0, q2, up); ce(q1, q3, up);
        ce(q0, q1, up); ce(q2, q3, up);
    }

    if (N == 4096u) {
        __syncthreads();
        *(uint4*)&lds[e0] = make_uint4(q0, q1, q2, q3);
        __syncthreads();
        const bool low = e0 < 2048u;
        if (low) {
            uint4 p = *(uint4*)&lds[e0 + 2048];
            q0 = q0 < p.x ? q0 : p.x; q1 = q1 < p.y ? q1 : p.y;
            q2 = q2 < p.z ? q2 : p.z; q3 = q3 < p.w ? q3 : p.w;
        }
        for (unsigned j = 1024; j >= 256u; j >>= 1) {
            __syncthreads();
            if (low) *(uint4*)&lds[e0] = make_uint4(q0, q1, q2, q3);
            __syncthreads();
            if (low) {
                uint4 p = *(uint4*)&lds[e0 ^ j];
                bool kl = (e0 & j) == 0;
                q0 = cd(q0, p.x, kl); q1 = cd(q1, p.y, kl);
                q2 = cd(q2, p.z, kl); q3 = cd(q3, p.w, kl);
            }
        }
        if (low) {
#pragma unroll
            for (unsigned j = 128; j >= 4u; j >>= 1) {
                bool kl = (e0 & j) == 0;
                int m = (int)(j >> 2);
                q0 = cd(q0, (unsigned)__shfl_xor((int)q0, m), kl);
                q1 = cd(q1, (unsigned)__shfl_xor((int)q1, m), kl);
                q2 = cd(q2, (unsigned)__shfl_xor((int)q2, m), kl);
                q3 = cd(q3, (unsigned)__shfl_xor((int)q3, m), kl);
            }
            ce(q0, q2, true); ce(q1, q3, true);
            ce(q0, q1, true); ce(q2, q3, true);
            float4 o = make_float4((float)(q0 & 0xFFFu), (float)(q1 & 0xFFFu),
                                   (float)(q2 & 0xFFFu), (float)(q3 & 0xFFFu));
            *(float4*)(outIdx + (size_t)row * TOPK_N + e0) = o;
        }
    } else {
        float4 o = make_float4((float)(q0 & 0xFFFu), (float)(q1 & 0xFFFu),
                               (float)(q2 & 0xFFFu), (float)(q3 & 0xFFFu));
        *(float4*)(outIdx + (size_t)row * TOPK_N + e0) = o;
    }
}

// ============================================================================
extern "C" void kernel_launch(void* const* d_in, const int* in_sizes, int n_in,
                              void* d_out, int out_size, void* d_ws, size_t ws_size,
                              hipStream_t stream) {
    const float* hs      = (const float*)d_in[0];
    const float* qr      = (const float*)d_in[1];
    const int*   pos     = (const int*)  d_in[2];
    const float* wq_b    = (const float*)d_in[3];
    const float* wk      = (const float*)d_in[4];
    const float* k_gamma = (const float*)d_in[5];
    const float* k_beta  = (const float*)d_in[6];
    const float* w_proj  = (const float*)d_in[7];

    float* out     = (float*)d_out;
    float* out_idx = out;
    float* S       = out + (size_t)T_DIM * TOPK_N;

    char* wsp = (char*)d_ws;
    unsigned char*  qfrag  = (unsigned char*)wsp;  wsp += (size_t)67108864;
    unsigned short* hsfrag = (unsigned short*)qfrag;  // alias: hs consumed before qfrag written
    unsigned char*  qrfrag = (unsigned char*)wsp;  wsp += (size_t)12582912;
    unsigned char*  wqfrag = (unsigned char*)wsp;  wsp += (size_t)25165824;
    unsigned short* wkwfrag= (unsigned short*)wsp; wsp += (size_t)2752512;
    float*          part   = (float*)wsp;          wsp += (size_t)12582912;
    float*          wT     = (float*)wsp;          wsp += (size_t)1048576;
    unsigned char*  kfrag  = (unsigned char*)wsp;  wsp += (size_t)1048576;
    float2*         tab    = (float2*)wsp;         wsp += (size_t)1048576;

    rope_tab_kernel<<<512, 256, 0, stream>>>(pos, tab);
    conv_afrag <<<3584, 256, 0, stream>>>(hs, hsfrag, HSZ, 224, 28);
    conv_wkw   <<<672,  256, 0, stream>>>(wk, w_proj, wkwfrag);
    kw_gemm_mfma<<<1024, 256, 0, stream>>>(hsfrag, wkwfrag, part);
    reduce_w   <<<64,   256, 0, stream>>>(part, wT);
    ln_rope_k  <<<T_DIM / 4, 256, 0, stream>>>(part, tab, k_gamma, k_beta, kfrag);
    conv_qr_fp8<<<768,  256, 0, stream>>>(qr, qrfrag);
    conv_wq_fp8<<<1536, 256, 0, stream>>>(wq_b, wqfrag);
    q_gemm_mfma<<<2048, 256, 0, stream>>>(qrfrag, wqfrag, tab, qfrag);
    scores_mfma<<<1056, 256, 0, stream>>>(qfrag, kfrag, wT, S);
    topk_kernel<<<3072, 1024, 0, stream>>>(S, out_idx);
}

// Round 15
// 447.798 us; speedup vs baseline: 2.2827x; 1.0512x over previous
//
#include <hip/hip_runtime.h>
#include <hip/hip_bf16.h>
#include <math.h>

#define T_DIM 4096
#define HSZ   7168
#define QLR_K 1536
#define NH    64
#define HD    128
#define QN    (NH*HD)   // 8192
#define TOPK_N 2048
#define MASK_VAL (-3.0e38f)
// 0.125 (w_proj scale) * 128^-0.5 (q scale, folded out of fp8 q for precision)
#define WSCALE 0.011048543456039806f

using short8 = __attribute__((ext_vector_type(8))) short;   // 8 bf16 (4 VGPR)
using f32x4  = __attribute__((ext_vector_type(4))) float;
using i32x8  = __attribute__((ext_vector_type(8))) int;     // fp8 x32 (8 VGPR)

#define MFMA16(a,b,c) __builtin_amdgcn_mfma_f32_16x16x32_bf16(a,b,c,0,0,0)
#define MFMA8(a,b,c)  __builtin_amdgcn_mfma_f32_16x16x32_fp8_fp8(a,b,c,0,0,0)
// MX-scaled K=128 fp8: fmt 0/0 = e4m3/e4m3, scale byte 127 = 2^0 = 1.0.
// k-permutation-invariant: identical subtile packing on A and B sides.
#define MFMA8S(a,b,c) __builtin_amdgcn_mfma_scale_f32_16x16x128_f8f6f4(a,b,c,0,0,0,127,0,127)

__device__ __forceinline__ float rope_invf(int d) {
    return (float)(1.0 / pow(10000.0, (double)d / 32.0));
}
__device__ __forceinline__ unsigned short f2bf(float f) {
    unsigned u = __float_as_uint(f);
    return (unsigned short)((u + 0x7FFFu + ((u >> 16) & 1u)) >> 16);
}
// HW fp8 e4m3 conversion (v_cvt_pk_fp8_f32, gfx940+)
__device__ __forceinline__ unsigned char f2fp8(float x) {
    return (unsigned char)(__builtin_amdgcn_cvt_pk_fp8_f32(x, x, 0, false) & 0xFF);
}
__device__ __forceinline__ unsigned pk4fp8(float a, float b, float c, float d) {
    unsigned w = (unsigned)__builtin_amdgcn_cvt_pk_fp8_f32(a, b, 0, false);
    return (unsigned)__builtin_amdgcn_cvt_pk_fp8_f32(c, d, (int)w, true);
}

// ============================================================================
// rope_tab
// ============================================================================
__global__ __launch_bounds__(256)
void rope_tab_kernel(const int* __restrict__ positions, float2* __restrict__ tab) {
    int idx = blockIdx.x * 256 + threadIdx.x;
    int t = idx >> 5, dd = idx & 31;
    float p = (float)positions[t];
    float ang = p * rope_invf(dd);
    float s, c; sincosf(ang, &s, &c);
    tab[idx] = make_float2(c, s);
}

// ============================================================================
// conv_afrag (bf16, for hs -> kw path)
// ============================================================================
__global__ __launch_bounds__(256)
void conv_afrag(const float* __restrict__ src, unsigned short* __restrict__ dst,
                int C, int KS, int ctiles) {
    __shared__ float lds[32][258];
    const int tid = threadIdx.x;
    const int rt = blockIdx.x / ctiles, ct = blockIdx.x - rt * ctiles;
    const int r0 = rt * 32, c0 = ct * 256;
#pragma unroll
    for (int it = 0; it < 8; ++it) {
        int fid = it * 256 + tid;
        int r = fid >> 6, c4 = (fid & 63) << 2;
        float4 v = *(const float4*)(src + (size_t)(r0 + r) * C + c0 + c4);
        lds[r][c4] = v.x; lds[r][c4 + 1] = v.y; lds[r][c4 + 2] = v.z; lds[r][c4 + 3] = v.w;
    }
    __syncthreads();
    const int lane = tid & 63, wid = tid >> 6;
#pragma unroll
    for (int j = 0; j < 4; ++j) {
        int s = wid * 4 + j;
        int ig_l = s >> 3, ks_l = s & 7;
        int r = ig_l * 16 + (lane & 15);
        int c = ks_l * 32 + ((lane >> 4) << 3);
        unsigned short o[8];
#pragma unroll
        for (int e = 0; e < 8; ++e) o[e] = f2bf(lds[r][c + e]);
        size_t ig = rt * 2 + ig_l, ks = (size_t)ct * 8 + ks_l;
        *(short8*)(dst + ((ig * KS + ks) * 64 + lane) * 8) = *(short8*)o;
    }
}

// ============================================================================
// conv_qr_fp8
// ============================================================================
__global__ __launch_bounds__(256)
void conv_qr_fp8(const float* __restrict__ src, unsigned char* __restrict__ dst) {
    __shared__ float lds[32][258];
    const int tid = threadIdx.x;
    const int rt = blockIdx.x / 6, ct = blockIdx.x - rt * 6;
    const int r0 = rt * 32, c0 = ct * 256;
#pragma unroll
    for (int it = 0; it < 8; ++it) {
        int fid = it * 256 + tid;
        int r = fid >> 6, c4 = (fid & 63) << 2;
        float4 v = *(const float4*)(src + (size_t)(r0 + r) * QLR_K + c0 + c4);
        lds[r][c4] = v.x; lds[r][c4 + 1] = v.y; lds[r][c4 + 2] = v.z; lds[r][c4 + 3] = v.w;
    }
    __syncthreads();
    const int lane = tid & 63, wid = tid >> 6;
#pragma unroll
    for (int j = 0; j < 4; ++j) {
        int s = wid * 4 + j;
        int ig_l = s >> 3, ks_l = s & 7;
        int r = ig_l * 16 + (lane & 15);
        int c = ks_l * 32 + ((lane >> 4) << 3);
        uint2 o;
        o.x = pk4fp8(lds[r][c], lds[r][c + 1], lds[r][c + 2], lds[r][c + 3]);
        o.y = pk4fp8(lds[r][c + 4], lds[r][c + 5], lds[r][c + 6], lds[r][c + 7]);
        size_t ig = rt * 2 + ig_l, ks = (size_t)ct * 8 + ks_l;
        *(uint2*)(dst + ((ig * 48 + ks) * 64 + lane) * 8) = o;
    }
}

// ============================================================================
// conv_wq_fp8
// ============================================================================
__global__ __launch_bounds__(256)
void conv_wq_fp8(const float* __restrict__ wq, unsigned char* __restrict__ dst) {
    __shared__ float lds[32][258];
    const int tid = threadIdx.x;
    const int kt = blockIdx.x >> 5, nt = blockIdx.x & 31;
    const int k0 = kt * 32, n0 = nt * 256;
#pragma unroll
    for (int it = 0; it < 8; ++it) {
        int fid = it * 256 + tid;
        int k = fid >> 6, c4 = (fid & 63) << 2;
        float4 v = *(const float4*)(wq + (size_t)(k0 + k) * QN + n0 + c4);
        lds[k][c4] = v.x; lds[k][c4 + 1] = v.y; lds[k][c4 + 2] = v.z; lds[k][c4 + 3] = v.w;
    }
    __syncthreads();
    const int lane = tid & 63, wid = tid >> 6;
#pragma unroll
    for (int j = 0; j < 4; ++j) {
        int s = wid * 4 + j;
        int n_l = s * 16 + (lane & 15);
        int kb = (lane >> 4) << 3;
        uint2 o;
        o.x = pk4fp8(lds[kb][n_l], lds[kb + 1][n_l], lds[kb + 2][n_l], lds[kb + 3][n_l]);
        o.y = pk4fp8(lds[kb + 4][n_l], lds[kb + 5][n_l], lds[kb + 6][n_l], lds[kb + 7][n_l]);
        size_t ng = (size_t)nt * 16 + s;
        *(uint2*)(dst + ((ng * 48 + kt) * 64 + lane) * 8) = o;
    }
}

// ============================================================================
// conv_wkw
// ============================================================================
__global__ __launch_bounds__(256)
void conv_wkw(const float* __restrict__ wk, const float* __restrict__ wp,
              unsigned short* __restrict__ dst) {
    int gid = blockIdx.x * 4 + (threadIdx.x >> 6);
    int lane = threadIdx.x & 63;
    int ng = gid / 224, ks = gid - ng * 224;
    int col = ng * 16 + (lane & 15);
    int k = ks * 32 + ((lane >> 4) << 3);
    unsigned short o[8];
#pragma unroll
    for (int e = 0; e < 8; ++e) {
        float v = (col < 128) ? wk[(size_t)(k + e) * 128 + col]
                              : wp[(size_t)(k + e) * 64 + (col - 128)];
        o[e] = f2bf(v);
    }
    *(short8*)(dst + ((size_t)gid * 64 + lane) * 8) = *(short8*)o;
}

// ============================================================================
// kw_gemm_mfma v2 (verified round 13)
// ============================================================================
__global__ __launch_bounds__(256, 4)
void kw_gemm_mfma(const unsigned short* __restrict__ hsfrag,
                  const unsigned short* __restrict__ wkwfrag,
                  float* __restrict__ part) {
    const int kz = blockIdx.x >> 8;              // 0..3
    const int ig = blockIdx.x & 255;             // 0..255
    const int lane = threadIdx.x & 63, wid = threadIdx.x >> 6;
    const f32x4 zed = {0.f, 0.f, 0.f, 0.f};
    f32x4 acc[3];
#pragma unroll
    for (int j = 0; j < 3; ++j) acc[j] = zed;

    const unsigned short* ap = hsfrag + ((size_t)ig * 224 * 64 + lane) * 8;
    const unsigned short* bp = wkwfrag + ((size_t)(wid * 3) * 224 * 64 + lane) * 8;
#pragma unroll 4
    for (int ks = kz * 56; ks < kz * 56 + 56; ++ks) {
        short8 a = *(const short8*)(ap + (size_t)ks * 512);
        short8 b0 = *(const short8*)(bp + (size_t)ks * 512);
        short8 b1 = *(const short8*)(bp + (size_t)(224 * 64 * 8) + (size_t)ks * 512);
        short8 b2 = *(const short8*)(bp + (size_t)(2 * 224 * 64 * 8) + (size_t)ks * 512);
        acc[0] = MFMA16(a, b0, acc[0]);
        acc[1] = MFMA16(a, b1, acc[1]);
        acc[2] = MFMA16(a, b2, acc[2]);
    }
    const int colc = lane & 15, rsub = (lane >> 4) << 2;
    float* pb = part + (size_t)kz * T_DIM * 192;
#pragma unroll
    for (int j = 0; j < 3; ++j) {
        int ng = wid * 3 + j;
#pragma unroll
        for (int r = 0; r < 4; ++r) {
            int row = ig * 16 + rsub + r;
            pb[(size_t)row * 192 + ng * 16 + colc] = acc[j][r];
        }
    }
}

// ============================================================================
// reduce_w
// ============================================================================
__global__ __launch_bounds__(256)
void reduce_w(const float* __restrict__ part, float* __restrict__ wT) {
    __shared__ float lds[64][65];
    const int r0 = blockIdx.x * 64;
    const int tid = threadIdx.x;
#pragma unroll
    for (int it = 0; it < 16; ++it) {
        int fid = it * 256 + tid;
        int rl = fid >> 6, h = fid & 63;
        float s = 0.f;
#pragma unroll
        for (int z = 0; z < 4; ++z)
            s += part[((size_t)z * T_DIM + r0 + rl) * 192 + 128 + h];
        lds[rl][h] = s * WSCALE;
    }
    __syncthreads();
#pragma unroll
    for (int it = 0; it < 16; ++it) {
        int fid = it * 256 + tid;
        int h = fid >> 6, rl = fid & 63;
        wT[(size_t)h * T_DIM + r0 + rl] = lds[rl][h];
    }
}

// ============================================================================
// ln_rope_k
// ============================================================================
__global__ __launch_bounds__(256)
void ln_rope_k(const float* __restrict__ part, const float2* __restrict__ tab,
               const float* __restrict__ gamma, const float* __restrict__ beta,
               unsigned char* __restrict__ kfrag) {
    __shared__ float ln[4][128];
    const int tid = threadIdx.x;
    const int wr = tid >> 6, lane = tid & 63;
    const int row = blockIdx.x * 4 + wr;
    float2 v = make_float2(0.f, 0.f);
#pragma unroll
    for (int z = 0; z < 4; ++z) {
        float2 p = *(const float2*)(part + ((size_t)z * T_DIM + row) * 192 + lane * 2);
        v.x += p.x; v.y += p.y;
    }
    float s = v.x + v.y;
#pragma unroll
    for (int off = 1; off < 64; off <<= 1) s += __shfl_xor(s, off);
    float mu = s * (1.0f / 128.0f);
    float d0 = v.x - mu, d1 = v.y - mu;
    float s2 = d0 * d0 + d1 * d1;
#pragma unroll
    for (int off = 1; off < 64; off <<= 1) s2 += __shfl_xor(s2, off);
    float rstd = 1.0f / sqrtf(s2 * (1.0f / 128.0f) + 1e-6f);
    ln[wr][lane * 2]     = d0 * rstd * gamma[lane * 2]     + beta[lane * 2];
    ln[wr][lane * 2 + 1] = d1 * rstd * gamma[lane * 2 + 1] + beta[lane * 2 + 1];
    __syncthreads();
    int d = lane * 2;
    float o0, o1;
    float v0 = ln[wr][d], v1 = ln[wr][d + 1];
    if (d < 64) {
        int dd = d & 31;
        float2 c0 = tab[(size_t)row * 32 + dd];
        float2 c1 = tab[(size_t)row * 32 + dd + 1];
        if (d < 32) {
            o0 = v0 * c0.x - ln[wr][d + 32] * c0.y;
            o1 = v1 * c1.x - ln[wr][d + 33] * c1.y;
        } else {
            o0 = v0 * c0.x + ln[wr][d - 32] * c0.y;
            o1 = v1 * c1.x + ln[wr][d - 31] * c1.y;
        }
    } else { o0 = v0; o1 = v1; }
    int jg = row >> 4, ks = d >> 5, sub = d & 31;
    int lp = ((sub >> 3) << 4) + (row & 15);
    size_t bidx = (((size_t)jg * 4 + ks) * 64 + lp) * 8 + (sub & 7);
    unsigned pk = (unsigned)__builtin_amdgcn_cvt_pk_fp8_f32(o0, o1, 0, false);
    *(unsigned short*)(kfrag + bidx) = (unsigned short)(pk & 0xFFFFu);
}

// ============================================================================
// q_gemm_mfma: fp8 x fp8 -> qfrag fp8 A-frag
// ============================================================================
__global__ __launch_bounds__(256, 4)
void q_gemm_mfma(const unsigned char* __restrict__ qr8,
                 const unsigned char* __restrict__ wq8,
                 const float2* __restrict__ tab,
                 unsigned char* __restrict__ qfrag) {
    const int hw = blockIdx.x;
    const int orig = (hw & 7) * 256 + (hw >> 3);
    const int head = orig >> 5, mt = orig & 31;
    const int tid = threadIdx.x, lane = tid & 63, wid = tid >> 6;
    const int wm = wid >> 1, wn = wid & 1;
    const f32x4 zed = {0.f, 0.f, 0.f, 0.f};
    f32x4 acc[4][4];
#pragma unroll
    for (int m = 0; m < 4; m++)
#pragma unroll
        for (int n = 0; n < 4; n++) acc[m][n] = zed;

    const int ig0 = mt * 8 + wm * 4;
    const int ng0 = head * 8 + wn * 4;
    const unsigned char* ap = qr8 + ((size_t)ig0 * 48 * 64 + lane) * 8;
    const unsigned char* bp = wq8 + ((size_t)ng0 * 48 * 64 + lane) * 8;
    for (int ks = 0; ks < 48; ++ks) {
        long a[4], b[4];
#pragma unroll
        for (int m = 0; m < 4; m++)
            a[m] = *(const long*)(ap + ((size_t)m * 48 + ks) * 512);
#pragma unroll
        for (int n = 0; n < 4; n++)
            b[n] = *(const long*)(bp + ((size_t)n * 48 + ks) * 512);
#pragma unroll
        for (int m = 0; m < 4; m++)
#pragma unroll
            for (int n = 0; n < 4; n++)
                acc[m][n] = MFMA8(a[m], b[n], acc[m][n]);
    }
    const int colc = lane & 15;
    const int rsub = (lane >> 4) << 2;
#pragma unroll
    for (int m = 0; m < 4; m++) {
#pragma unroll
        for (int r = 0; r < 4; r++) {
            int row = mt * 128 + wm * 64 + m * 16 + rsub + r;
            int rl = rsub + r;
            size_t base = ((size_t)(row >> 4) * 64 + head) * 4;
            if (wn == 0) {
#pragma unroll
                for (int n2 = 0; n2 < 2; n2++) {
                    int dd = n2 * 16 + colc;
                    float2 cs = tab[(size_t)row * 32 + dd];
                    float x1 = acc[m][n2][r], x2 = acc[m][n2 + 2][r];
                    float olo = x1 * cs.x - x2 * cs.y;
                    float ohi = x2 * cs.x + x1 * cs.y;
                    int lp = ((dd >> 3) << 4) + rl;
                    qfrag[((base + 0) * 64 + lp) * 8 + (dd & 7)] = f2fp8(olo);
                    qfrag[((base + 1) * 64 + lp) * 8 + (dd & 7)] = f2fp8(ohi);
                }
            } else {
#pragma unroll
                for (int n = 0; n < 4; n++) {
                    int d = 64 + n * 16 + colc;
                    int ks2 = d >> 5, sub = d & 31;
                    int lp = ((sub >> 3) << 4) + rl;
                    qfrag[((base + ks2) * 64 + lp) * 8 + (sub & 7)] = f2fp8(acc[m][n][r]);
                }
            }
        }
    }
}

// ============================================================================
// scores_mfma v9: MX-scaled K=128 fp8 MFMA (one MFMA per m,n,h instead of 4;
// 2x pipe rate). Operands are the four verified 32-k subtile fragments
// concatenated -- correct for ANY true HW k-mapping because A and B use the
// same packing (k-permutation invariance of the dot product). C/D layout is
// shape-determined (== 16x16x32), so epilogue unchanged.
// 64x128 tiles, 1056 blocks, 4 waves 2x2, register Q double-buffer across h.
// ============================================================================
#define LOAD_H(A, hh)                                                          \
    _Pragma("unroll")                                                          \
    for (int m_ = 0; m_ < 2; ++m_) {                                           \
        int2 t0_ = *(const int2*)(qb[m_] + (size_t)(hh) * 2048 + 0 * 512);     \
        int2 t1_ = *(const int2*)(qb[m_] + (size_t)(hh) * 2048 + 1 * 512);     \
        int2 t2_ = *(const int2*)(qb[m_] + (size_t)(hh) * 2048 + 2 * 512);     \
        int2 t3_ = *(const int2*)(qb[m_] + (size_t)(hh) * 2048 + 3 * 512);     \
        A[m_] = (i32x8){t0_.x, t0_.y, t1_.x, t1_.y,                            \
                        t2_.x, t2_.y, t3_.x, t3_.y};                           \
    }

#define COMPUTE_H(A, hh)                                                       \
    _Pragma("unroll")                                                          \
    for (int m_ = 0; m_ < 2; ++m_) {                                           \
        f32x4 s0 = MFMA8S(A[m_], kf8[0], zed);                                 \
        f32x4 s1 = MFMA8S(A[m_], kf8[1], zed);                                 \
        f32x4 s2 = MFMA8S(A[m_], kf8[2], zed);                                 \
        f32x4 s3 = MFMA8S(A[m_], kf8[3], zed);                                 \
        f32x4 wv = *(const f32x4*)&wlds[hh][wm * 32 + m_ * 16 + rsub];         \
        _Pragma("unroll")                                                      \
        for (int rr_ = 0; rr_ < 4; ++rr_) {                                    \
            acc[m_][0][rr_] += wv[rr_] * fmaxf(s0[rr_], 0.0f);                 \
            acc[m_][1][rr_] += wv[rr_] * fmaxf(s1[rr_], 0.0f);                 \
            acc[m_][2][rr_] += wv[rr_] * fmaxf(s2[rr_], 0.0f);                 \
            acc[m_][3][rr_] += wv[rr_] * fmaxf(s3[rr_], 0.0f);                 \
        }                                                                      \
    }

__global__ __launch_bounds__(256)
void scores_mfma(const unsigned char* __restrict__ qfrag,
                 const unsigned char* __restrict__ kfrag,
                 const float* __restrict__ wT, float* __restrict__ S) {
    const int bid = blockIdx.x;                  // 0..1055
    int u = (int)((sqrtf(4.f * bid + 1.f) - 1.f) * 0.5f);
    while ((u + 1) * (u + 2) <= bid) ++u;
    while (u * (u + 1) > bid) --u;
    int r_ = bid - u * (u + 1);                  // 0..2u+1
    const int byp = (r_ <= u) ? 2 * u : 2 * u + 1;
    const int jt  = (r_ <= u) ? r_ : r_ - (u + 1);
    __shared__ float wlds[64][64];
    const int tid = threadIdx.x;
    const int lane = tid & 63, wid = tid >> 6;
    const int wm = wid >> 1, wn = wid & 1;       // 2 x 2
    const int i0 = byp * 64, j0 = jt * 128;
    const f32x4 zed = {0.f, 0.f, 0.f, 0.f};
#pragma unroll
    for (int it = 0; it < 16; ++it) {
        int fid = it * 256 + tid;
        int hh = fid >> 6, rl = fid & 63;
        wlds[hh][rl] = wT[(size_t)hh * T_DIM + i0 + rl];
    }
    i32x8 kf8[4];
#pragma unroll
    for (int n = 0; n < 4; ++n) {
        int jg = (j0 >> 4) + wn * 4 + n;
        const unsigned char* kb = kfrag + ((size_t)jg * 4 * 64 + lane) * 8;
        int2 u0 = *(const int2*)(kb + 0 * 512);
        int2 u1 = *(const int2*)(kb + 1 * 512);
        int2 u2 = *(const int2*)(kb + 2 * 512);
        int2 u3 = *(const int2*)(kb + 3 * 512);
        kf8[n] = (i32x8){u0.x, u0.y, u1.x, u1.y, u2.x, u2.y, u3.x, u3.y};
    }
    __syncthreads();

    f32x4 acc[2][4];
#pragma unroll
    for (int m = 0; m < 2; m++)
#pragma unroll
        for (int n = 0; n < 4; n++) acc[m][n] = zed;

    const int rsub = (lane >> 4) << 2;
    const unsigned char* qb[2];
#pragma unroll
    for (int m = 0; m < 2; ++m) {
        int ig = byp * 4 + wm * 2 + m;
        qb[m] = qfrag + (size_t)ig * 64 * 2048 + lane * 8;
    }

    i32x8 a0[2], a1[2];
    LOAD_H(a0, 0)
    for (int h = 0; h < NH; h += 2) {
        LOAD_H(a1, h + 1)          // prefetch h+1; waits land after COMPUTE(a0)
        COMPUTE_H(a0, h)
        if (h + 2 < NH) { LOAD_H(a0, h + 2) }
        COMPUTE_H(a1, h + 1)
    }

    const int colc = lane & 15;
#pragma unroll
    for (int m = 0; m < 2; m++) {
#pragma unroll
        for (int n = 0; n < 4; n++) {
            int col = j0 + wn * 64 + n * 16 + colc;
#pragma unroll
            for (int rr = 0; rr < 4; rr++) {
                int row = i0 + wm * 32 + m * 16 + rsub + rr;
                float v = acc[m][n][rr];
                if (col > row) v = MASK_VAL;
                S[(size_t)row * T_DIM + col] = v;
            }
        }
    }
}

// ============================================================================
// topk v5: masked positions (p > row) synthesized as 0xFFFFF000|p keys.
// ============================================================================
__device__ __forceinline__ void ce(unsigned &x, unsigned &y, bool up) {
    unsigned lo = x < y ? x : y, hi = x < y ? y : x;
    x = up ? lo : hi; y = up ? hi : lo;
}
__device__ __forceinline__ unsigned cd(unsigned a, unsigned b, bool keep_lo) {
    unsigned lo = a < b ? a : b, hi = a < b ? b : a;
    return keep_lo ? lo : hi;
}

__global__ __launch_bounds__(1024)
void topk_kernel(const float* __restrict__ S, float* __restrict__ outIdx) {
    __shared__ unsigned lds[4096];
    const int bid = blockIdx.x;
    const int tid = threadIdx.x;

    unsigned q0, q1, q2, q3;
    int row; unsigned e0; unsigned* L;

    if (bid < 1024) {            // two short rows per block
        const int half = tid >> 9;
        row = bid * 2 + half;
        e0 = 4u * (tid & 511);
        L = &lds[half * 2048];
    } else {                     // one long row
        row = bid + 1024;
        e0 = 4u * tid;
        L = lds;
    }
    const unsigned N = (bid < 1024) ? 2048u : 4096u;

    {   // load + pack keys (masked p>row synthesized) + stages k=2,4
        float4 f = *(const float4*)(S + (size_t)row * T_DIM + e0);
        const float* fp = &f.x;
        unsigned qq[4];
#pragma unroll
        for (int e = 0; e < 4; ++e) {
            unsigned p = e0 + e;
            unsigned u = __float_as_uint(fp[e]);
            u = (u & 0x80000000u) ? ~u : (u | 0x80000000u);
            unsigned key = ((~u) & 0xFFFFF000u) | p;
            qq[e] = ((int)p > row) ? (0xFFFFF000u | p) : key;
        }
        q0 = qq[0]; q1 = qq[1]; q2 = qq[2]; q3 = qq[3];
        ce(q0, q1, true); ce(q2, q3, false);           // k=2
        bool up4 = (e0 & 4u) == 0;                     // k=4
        ce(q0, q2, up4); ce(q1, q3, up4);
        ce(q0, q1, up4); ce(q2, q3, up4);
    }

    for (unsigned k = 8; k <= 2048u; k <<= 1) {
        for (unsigned j = k >> 1; j >= 4u; j >>= 1) {
            bool kl = ((e0 & k) == 0) ^ ((e0 & j) != 0);
            if (j >= 256u) {
                __syncthreads();
                *(uint4*)&L[e0] = make_uint4(q0, q1, q2, q3);
                __syncthreads();
                uint4 p = *(uint4*)&L[e0 ^ j];
                q0 = cd(q0, p.x, kl); q1 = cd(q1, p.y, kl);
                q2 = cd(q2, p.z, kl); q3 = cd(q3, p.w, kl);
            } else {
                int m = (int)(j >> 2);
                q0 = cd(q0, (unsigned)__shfl_xor((int)q0, m), kl);
                q1 = cd(q1, (unsigned)__shfl_xor((int)q1, m), kl);
                q2 = cd(q2, (unsigned)__shfl_xor((int)q2, m), kl);
                q3 = cd(q3, (unsigned)__shfl_xor((int)q3, m), kl);
            }
        }
        bool up = ((e0 & k) == 0);                     // j=2,1 in regs
        ce(q0, q2, up); ce(q1, q3, up);
        ce(q0, q1, up); ce(q2, q3, up);
    }

    if (N == 4096u) {
        __syncthreads();
        *(uint4*)&lds[e0] = make_uint4(q0, q1, q2, q3);
        __syncthreads();
        const bool low = e0 < 2048u;
        if (low) {
            uint4 p = *(uint4*)&lds[e0 + 2048];
            q0 = q0 < p.x ? q0 : p.x; q1 = q1 < p.y ? q1 : p.y;
            q2 = q2 < p.z ? q2 : p.z; q3 = q3 < p.w ? q3 : p.w;
        }
        for (unsigned j = 1024; j >= 256u; j >>= 1) {
            __syncthreads();
            if (low) *(uint4*)&lds[e0] = make_uint4(q0, q1, q2, q3);
            __syncthreads();
            if (low) {
                uint4 p = *(uint4*)&lds[e0 ^ j];
                bool kl = (e0 & j) == 0;
                q0 = cd(q0, p.x, kl); q1 = cd(q1, p.y, kl);
                q2 = cd(q2, p.z, kl); q3 = cd(q3, p.w, kl);
            }
        }
        if (low) {
#pragma unroll
            for (unsigned j = 128; j >= 4u; j >>= 1) {
                bool kl = (e0 & j) == 0;
                int m = (int)(j >> 2);
                q0 = cd(q0, (unsigned)__shfl_xor((int)q0, m), kl);
                q1 = cd(q1, (unsigned)__shfl_xor((int)q1, m), kl);
                q2 = cd(q2, (unsigned)__shfl_xor((int)q2, m), kl);
                q3 = cd(q3, (unsigned)__shfl_xor((int)q3, m), kl);
            }
            ce(q0, q2, true); ce(q1, q3, true);
            ce(q0, q1, true); ce(q2, q3, true);
            float4 o = make_float4((float)(q0 & 0xFFFu), (float)(q1 & 0xFFFu),
                                   (float)(q2 & 0xFFFu), (float)(q3 & 0xFFFu));
            *(float4*)(outIdx + (size_t)row * TOPK_N + e0) = o;
        }
    } else {
        float4 o = make_float4((float)(q0 & 0xFFFu), (float)(q1 & 0xFFFu),
                               (float)(q2 & 0xFFFu), (float)(q3 & 0xFFFu));
        *(float4*)(outIdx + (size_t)row * TOPK_N + e0) = o;
    }
}

// ============================================================================
extern "C" void kernel_launch(void* const* d_in, const int* in_sizes, int n_in,
                              void* d_out, int out_size, void* d_ws, size_t ws_size,
                              hipStream_t stream) {
    const float* hs      = (const float*)d_in[0];
    const float* qr      = (const float*)d_in[1];
    const int*   pos     = (const int*)  d_in[2];
    const float* wq_b    = (const float*)d_in[3];
    const float* wk      = (const float*)d_in[4];
    const float* k_gamma = (const float*)d_in[5];
    const float* k_beta  = (const float*)d_in[6];
    const float* w_proj  = (const float*)d_in[7];

    float* out     = (float*)d_out;
    float* out_idx = out;
    float* S       = out + (size_t)T_DIM * TOPK_N;

    char* wsp = (char*)d_ws;
    unsigned char*  qfrag  = (unsigned char*)wsp;  wsp += (size_t)67108864;
    unsigned short* hsfrag = (unsigned short*)qfrag;  // alias: hs consumed before qfrag written
    unsigned char*  qrfrag = (unsigned char*)wsp;  wsp += (size_t)12582912;
    unsigned char*  wqfrag = (unsigned char*)wsp;  wsp += (size_t)25165824;
    unsigned short* wkwfrag= (unsigned short*)wsp; wsp += (size_t)2752512;
    float*          part   = (float*)wsp;          wsp += (size_t)12582912;
    float*          wT     = (float*)wsp;          wsp += (size_t)1048576;
    unsigned char*  kfrag  = (unsigned char*)wsp;  wsp += (size_t)1048576;
    float2*         tab    = (float2*)wsp;         wsp += (size_t)1048576;

    rope_tab_kernel<<<512, 256, 0, stream>>>(pos, tab);
    conv_afrag <<<3584, 256, 0, stream>>>(hs, hsfrag, HSZ, 224, 28);
    conv_wkw   <<<672,  256, 0, stream>>>(wk, w_proj, wkwfrag);
    kw_gemm_mfma<<<1024, 256, 0, stream>>>(hsfrag, wkwfrag, part);
    reduce_w   <<<64,   256, 0, stream>>>(part, wT);
    ln_rope_k  <<<T_DIM / 4, 256, 0, stream>>>(part, tab, k_gamma, k_beta, kfrag);
    conv_qr_fp8<<<768,  256, 0, stream>>>(qr, qrfrag);
    conv_wq_fp8<<<1536, 256, 0, stream>>>(wq_b, wqfrag);
    q_gemm_mfma<<<2048, 256, 0, stream>>>(qrfrag, wqfrag, tab, qfrag);
    scores_mfma<<<1056, 256, 0, stream>>>(qfrag, kfrag, wT, S);
    topk_kernel<<<3072, 1024, 0, stream>>>(S, out_idx);
}

// Round 16
// 433.705 us; speedup vs baseline: 2.3569x; 1.0325x over previous
//
#include <hip/hip_runtime.h>
#include <hip/hip_bf16.h>
#include <math.h>

#define T_DIM 4096
#define HSZ   7168
#define QLR_K 1536
#define NH    64
#define HD    128
#define QN    (NH*HD)   // 8192
#define TOPK_N 2048
#define MASK_VAL (-3.0e38f)
// 0.125 (w_proj scale) * 128^-0.5 (q scale, folded out of fp8 q for precision)
#define WSCALE 0.011048543456039806f

using short8 = __attribute__((ext_vector_type(8))) short;   // 8 bf16 (4 VGPR)
using f32x4  = __attribute__((ext_vector_type(4))) float;
using i32x8  = __attribute__((ext_vector_type(8))) int;     // fp8 x32 (8 VGPR)

#define MFMA16(a,b,c) __builtin_amdgcn_mfma_f32_16x16x32_bf16(a,b,c,0,0,0)
#define MFMA8(a,b,c)  __builtin_amdgcn_mfma_f32_16x16x32_fp8_fp8(a,b,c,0,0,0)
// MX-scaled K=128 fp8: fmt 0/0 = e4m3/e4m3, scale byte 127 = 2^0 = 1.0.
#define MFMA8S(a,b,c) __builtin_amdgcn_mfma_scale_f32_16x16x128_f8f6f4(a,b,c,0,0,0,127,0,127)

__device__ __forceinline__ float rope_invf(int d) {
    return (float)(1.0 / pow(10000.0, (double)d / 32.0));
}
__device__ __forceinline__ unsigned short f2bf(float f) {
    unsigned u = __float_as_uint(f);
    return (unsigned short)((u + 0x7FFFu + ((u >> 16) & 1u)) >> 16);
}
// HW fp8 e4m3 conversion (v_cvt_pk_fp8_f32, gfx940+)
__device__ __forceinline__ unsigned char f2fp8(float x) {
    return (unsigned char)(__builtin_amdgcn_cvt_pk_fp8_f32(x, x, 0, false) & 0xFF);
}
__device__ __forceinline__ unsigned pk4fp8(float a, float b, float c, float d) {
    unsigned w = (unsigned)__builtin_amdgcn_cvt_pk_fp8_f32(a, b, 0, false);
    return (unsigned)__builtin_amdgcn_cvt_pk_fp8_f32(c, d, (int)w, true);
}

// ============================================================================
// rope_tab
// ============================================================================
__global__ __launch_bounds__(256)
void rope_tab_kernel(const int* __restrict__ positions, float2* __restrict__ tab) {
    int idx = blockIdx.x * 256 + threadIdx.x;
    int t = idx >> 5, dd = idx & 31;
    float p = (float)positions[t];
    float ang = p * rope_invf(dd);
    float s, c; sincosf(ang, &s, &c);
    tab[idx] = make_float2(c, s);
}

// ============================================================================
// conv_afrag (bf16, for hs -> kw path)
// ============================================================================
__global__ __launch_bounds__(256)
void conv_afrag(const float* __restrict__ src, unsigned short* __restrict__ dst,
                int C, int KS, int ctiles) {
    __shared__ float lds[32][258];
    const int tid = threadIdx.x;
    const int rt = blockIdx.x / ctiles, ct = blockIdx.x - rt * ctiles;
    const int r0 = rt * 32, c0 = ct * 256;
#pragma unroll
    for (int it = 0; it < 8; ++it) {
        int fid = it * 256 + tid;
        int r = fid >> 6, c4 = (fid & 63) << 2;
        float4 v = *(const float4*)(src + (size_t)(r0 + r) * C + c0 + c4);
        lds[r][c4] = v.x; lds[r][c4 + 1] = v.y; lds[r][c4 + 2] = v.z; lds[r][c4 + 3] = v.w;
    }
    __syncthreads();
    const int lane = tid & 63, wid = tid >> 6;
#pragma unroll
    for (int j = 0; j < 4; ++j) {
        int s = wid * 4 + j;
        int ig_l = s >> 3, ks_l = s & 7;
        int r = ig_l * 16 + (lane & 15);
        int c = ks_l * 32 + ((lane >> 4) << 3);
        unsigned short o[8];
#pragma unroll
        for (int e = 0; e < 8; ++e) o[e] = f2bf(lds[r][c + e]);
        size_t ig = rt * 2 + ig_l, ks = (size_t)ct * 8 + ks_l;
        *(short8*)(dst + ((ig * KS + ks) * 64 + lane) * 8) = *(short8*)o;
    }
}

// ============================================================================
// conv_qr_fp8
// ============================================================================
__global__ __launch_bounds__(256)
void conv_qr_fp8(const float* __restrict__ src, unsigned char* __restrict__ dst) {
    __shared__ float lds[32][258];
    const int tid = threadIdx.x;
    const int rt = blockIdx.x / 6, ct = blockIdx.x - rt * 6;
    const int r0 = rt * 32, c0 = ct * 256;
#pragma unroll
    for (int it = 0; it < 8; ++it) {
        int fid = it * 256 + tid;
        int r = fid >> 6, c4 = (fid & 63) << 2;
        float4 v = *(const float4*)(src + (size_t)(r0 + r) * QLR_K + c0 + c4);
        lds[r][c4] = v.x; lds[r][c4 + 1] = v.y; lds[r][c4 + 2] = v.z; lds[r][c4 + 3] = v.w;
    }
    __syncthreads();
    const int lane = tid & 63, wid = tid >> 6;
#pragma unroll
    for (int j = 0; j < 4; ++j) {
        int s = wid * 4 + j;
        int ig_l = s >> 3, ks_l = s & 7;
        int r = ig_l * 16 + (lane & 15);
        int c = ks_l * 32 + ((lane >> 4) << 3);
        uint2 o;
        o.x = pk4fp8(lds[r][c], lds[r][c + 1], lds[r][c + 2], lds[r][c + 3]);
        o.y = pk4fp8(lds[r][c + 4], lds[r][c + 5], lds[r][c + 6], lds[r][c + 7]);
        size_t ig = rt * 2 + ig_l, ks = (size_t)ct * 8 + ks_l;
        *(uint2*)(dst + ((ig * 48 + ks) * 64 + lane) * 8) = o;
    }
}

// ============================================================================
// conv_wq_fp8
// ============================================================================
__global__ __launch_bounds__(256)
void conv_wq_fp8(const float* __restrict__ wq, unsigned char* __restrict__ dst) {
    __shared__ float lds[32][258];
    const int tid = threadIdx.x;
    const int kt = blockIdx.x >> 5, nt = blockIdx.x & 31;
    const int k0 = kt * 32, n0 = nt * 256;
#pragma unroll
    for (int it = 0; it < 8; ++it) {
        int fid = it * 256 + tid;
        int k = fid >> 6, c4 = (fid & 63) << 2;
        float4 v = *(const float4*)(wq + (size_t)(k0 + k) * QN + n0 + c4);
        lds[k][c4] = v.x; lds[k][c4 + 1] = v.y; lds[k][c4 + 2] = v.z; lds[k][c4 + 3] = v.w;
    }
    __syncthreads();
    const int lane = tid & 63, wid = tid >> 6;
#pragma unroll
    for (int j = 0; j < 4; ++j) {
        int s = wid * 4 + j;
        int n_l = s * 16 + (lane & 15);
        int kb = (lane >> 4) << 3;
        uint2 o;
        o.x = pk4fp8(lds[kb][n_l], lds[kb + 1][n_l], lds[kb + 2][n_l], lds[kb + 3][n_l]);
        o.y = pk4fp8(lds[kb + 4][n_l], lds[kb + 5][n_l], lds[kb + 6][n_l], lds[kb + 7][n_l]);
        size_t ng = (size_t)nt * 16 + s;
        *(uint2*)(dst + ((ng * 48 + kt) * 64 + lane) * 8) = o;
    }
}

// ============================================================================
// conv_wkw
// ============================================================================
__global__ __launch_bounds__(256)
void conv_wkw(const float* __restrict__ wk, const float* __restrict__ wp,
              unsigned short* __restrict__ dst) {
    int gid = blockIdx.x * 4 + (threadIdx.x >> 6);
    int lane = threadIdx.x & 63;
    int ng = gid / 224, ks = gid - ng * 224;
    int col = ng * 16 + (lane & 15);
    int k = ks * 32 + ((lane >> 4) << 3);
    unsigned short o[8];
#pragma unroll
    for (int e = 0; e < 8; ++e) {
        float v = (col < 128) ? wk[(size_t)(k + e) * 128 + col]
                              : wp[(size_t)(k + e) * 64 + (col - 128)];
        o[e] = f2bf(v);
    }
    *(short8*)(dst + ((size_t)gid * 64 + lane) * 8) = *(short8*)o;
}

// ============================================================================
// kw_gemm_mfma v2 (verified round 13)
// ============================================================================
__global__ __launch_bounds__(256, 4)
void kw_gemm_mfma(const unsigned short* __restrict__ hsfrag,
                  const unsigned short* __restrict__ wkwfrag,
                  float* __restrict__ part) {
    const int kz = blockIdx.x >> 8;              // 0..3
    const int ig = blockIdx.x & 255;             // 0..255
    const int lane = threadIdx.x & 63, wid = threadIdx.x >> 6;
    const f32x4 zed = {0.f, 0.f, 0.f, 0.f};
    f32x4 acc[3];
#pragma unroll
    for (int j = 0; j < 3; ++j) acc[j] = zed;

    const unsigned short* ap = hsfrag + ((size_t)ig * 224 * 64 + lane) * 8;
    const unsigned short* bp = wkwfrag + ((size_t)(wid * 3) * 224 * 64 + lane) * 8;
#pragma unroll 4
    for (int ks = kz * 56; ks < kz * 56 + 56; ++ks) {
        short8 a = *(const short8*)(ap + (size_t)ks * 512);
        short8 b0 = *(const short8*)(bp + (size_t)ks * 512);
        short8 b1 = *(const short8*)(bp + (size_t)(224 * 64 * 8) + (size_t)ks * 512);
        short8 b2 = *(const short8*)(bp + (size_t)(2 * 224 * 64 * 8) + (size_t)ks * 512);
        acc[0] = MFMA16(a, b0, acc[0]);
        acc[1] = MFMA16(a, b1, acc[1]);
        acc[2] = MFMA16(a, b2, acc[2]);
    }
    const int colc = lane & 15, rsub = (lane >> 4) << 2;
    float* pb = part + (size_t)kz * T_DIM * 192;
#pragma unroll
    for (int j = 0; j < 3; ++j) {
        int ng = wid * 3 + j;
#pragma unroll
        for (int r = 0; r < 4; ++r) {
            int row = ig * 16 + rsub + r;
            pb[(size_t)row * 192 + ng * 16 + colc] = acc[j][r];
        }
    }
}

// ============================================================================
// reduce_w
// ============================================================================
__global__ __launch_bounds__(256)
void reduce_w(const float* __restrict__ part, float* __restrict__ wT) {
    __shared__ float lds[64][65];
    const int r0 = blockIdx.x * 64;
    const int tid = threadIdx.x;
#pragma unroll
    for (int it = 0; it < 16; ++it) {
        int fid = it * 256 + tid;
        int rl = fid >> 6, h = fid & 63;
        float s = 0.f;
#pragma unroll
        for (int z = 0; z < 4; ++z)
            s += part[((size_t)z * T_DIM + r0 + rl) * 192 + 128 + h];
        lds[rl][h] = s * WSCALE;
    }
    __syncthreads();
#pragma unroll
    for (int it = 0; it < 16; ++it) {
        int fid = it * 256 + tid;
        int h = fid >> 6, rl = fid & 63;
        wT[(size_t)h * T_DIM + r0 + rl] = lds[rl][h];
    }
}

// ============================================================================
// ln_rope_k
// ============================================================================
__global__ __launch_bounds__(256)
void ln_rope_k(const float* __restrict__ part, const float2* __restrict__ tab,
               const float* __restrict__ gamma, const float* __restrict__ beta,
               unsigned char* __restrict__ kfrag) {
    __shared__ float ln[4][128];
    const int tid = threadIdx.x;
    const int wr = tid >> 6, lane = tid & 63;
    const int row = blockIdx.x * 4 + wr;
    float2 v = make_float2(0.f, 0.f);
#pragma unroll
    for (int z = 0; z < 4; ++z) {
        float2 p = *(const float2*)(part + ((size_t)z * T_DIM + row) * 192 + lane * 2);
        v.x += p.x; v.y += p.y;
    }
    float s = v.x + v.y;
#pragma unroll
    for (int off = 1; off < 64; off <<= 1) s += __shfl_xor(s, off);
    float mu = s * (1.0f / 128.0f);
    float d0 = v.x - mu, d1 = v.y - mu;
    float s2 = d0 * d0 + d1 * d1;
#pragma unroll
    for (int off = 1; off < 64; off <<= 1) s2 += __shfl_xor(s2, off);
    float rstd = 1.0f / sqrtf(s2 * (1.0f / 128.0f) + 1e-6f);
    ln[wr][lane * 2]     = d0 * rstd * gamma[lane * 2]     + beta[lane * 2];
    ln[wr][lane * 2 + 1] = d1 * rstd * gamma[lane * 2 + 1] + beta[lane * 2 + 1];
    __syncthreads();
    int d = lane * 2;
    float o0, o1;
    float v0 = ln[wr][d], v1 = ln[wr][d + 1];
    if (d < 64) {
        int dd = d & 31;
        float2 c0 = tab[(size_t)row * 32 + dd];
        float2 c1 = tab[(size_t)row * 32 + dd + 1];
        if (d < 32) {
            o0 = v0 * c0.x - ln[wr][d + 32] * c0.y;
            o1 = v1 * c1.x - ln[wr][d + 33] * c1.y;
        } else {
            o0 = v0 * c0.x + ln[wr][d - 32] * c0.y;
            o1 = v1 * c1.x + ln[wr][d - 31] * c1.y;
        }
    } else { o0 = v0; o1 = v1; }
    int jg = row >> 4, ks = d >> 5, sub = d & 31;
    int lp = ((sub >> 3) << 4) + (row & 15);
    size_t bidx = (((size_t)jg * 4 + ks) * 64 + lp) * 8 + (sub & 7);
    unsigned pk = (unsigned)__builtin_amdgcn_cvt_pk_fp8_f32(o0, o1, 0, false);
    *(unsigned short*)(kfrag + bidx) = (unsigned short)(pk & 0xFFFFu);
}

// ============================================================================
// q_gemm_mfma: fp8 x fp8 -> qfrag fp8 A-frag
// ============================================================================
__global__ __launch_bounds__(256, 4)
void q_gemm_mfma(const unsigned char* __restrict__ qr8,
                 const unsigned char* __restrict__ wq8,
                 const float2* __restrict__ tab,
                 unsigned char* __restrict__ qfrag) {
    const int hw = blockIdx.x;
    const int orig = (hw & 7) * 256 + (hw >> 3);
    const int head = orig >> 5, mt = orig & 31;
    const int tid = threadIdx.x, lane = tid & 63, wid = tid >> 6;
    const int wm = wid >> 1, wn = wid & 1;
    const f32x4 zed = {0.f, 0.f, 0.f, 0.f};
    f32x4 acc[4][4];
#pragma unroll
    for (int m = 0; m < 4; m++)
#pragma unroll
        for (int n = 0; n < 4; n++) acc[m][n] = zed;

    const int ig0 = mt * 8 + wm * 4;
    const int ng0 = head * 8 + wn * 4;
    const unsigned char* ap = qr8 + ((size_t)ig0 * 48 * 64 + lane) * 8;
    const unsigned char* bp = wq8 + ((size_t)ng0 * 48 * 64 + lane) * 8;
    for (int ks = 0; ks < 48; ++ks) {
        long a[4], b[4];
#pragma unroll
        for (int m = 0; m < 4; m++)
            a[m] = *(const long*)(ap + ((size_t)m * 48 + ks) * 512);
#pragma unroll
        for (int n = 0; n < 4; n++)
            b[n] = *(const long*)(bp + ((size_t)n * 48 + ks) * 512);
#pragma unroll
        for (int m = 0; m < 4; m++)
#pragma unroll
            for (int n = 0; n < 4; n++)
                acc[m][n] = MFMA8(a[m], b[n], acc[m][n]);
    }
    const int colc = lane & 15;
    const int rsub = (lane >> 4) << 2;
#pragma unroll
    for (int m = 0; m < 4; m++) {
#pragma unroll
        for (int r = 0; r < 4; r++) {
            int row = mt * 128 + wm * 64 + m * 16 + rsub + r;
            int rl = rsub + r;
            size_t base = ((size_t)(row >> 4) * 64 + head) * 4;
            if (wn == 0) {
#pragma unroll
                for (int n2 = 0; n2 < 2; n2++) {
                    int dd = n2 * 16 + colc;
                    float2 cs = tab[(size_t)row * 32 + dd];
                    float x1 = acc[m][n2][r], x2 = acc[m][n2 + 2][r];
                    float olo = x1 * cs.x - x2 * cs.y;
                    float ohi = x2 * cs.x + x1 * cs.y;
                    int lp = ((dd >> 3) << 4) + rl;
                    qfrag[((base + 0) * 64 + lp) * 8 + (dd & 7)] = f2fp8(olo);
                    qfrag[((base + 1) * 64 + lp) * 8 + (dd & 7)] = f2fp8(ohi);
                }
            } else {
#pragma unroll
                for (int n = 0; n < 4; n++) {
                    int d = 64 + n * 16 + colc;
                    int ks2 = d >> 5, sub = d & 31;
                    int lp = ((sub >> 3) << 4) + rl;
                    qfrag[((base + ks2) * 64 + lp) * 8 + (sub & 7)] = f2fp8(acc[m][n][r]);
                }
            }
        }
    }
}

// ============================================================================
// scores_mfma v9 (verified round 15): MX-scaled K=128 fp8, 64x128 tiles,
// 1056 blocks, register Q double-buffer across h.
// ============================================================================
#define LOAD_H(A, hh)                                                          \
    _Pragma("unroll")                                                          \
    for (int m_ = 0; m_ < 2; ++m_) {                                           \
        int2 t0_ = *(const int2*)(qb[m_] + (size_t)(hh) * 2048 + 0 * 512);     \
        int2 t1_ = *(const int2*)(qb[m_] + (size_t)(hh) * 2048 + 1 * 512);     \
        int2 t2_ = *(const int2*)(qb[m_] + (size_t)(hh) * 2048 + 2 * 512);     \
        int2 t3_ = *(const int2*)(qb[m_] + (size_t)(hh) * 2048 + 3 * 512);     \
        A[m_] = (i32x8){t0_.x, t0_.y, t1_.x, t1_.y,                            \
                        t2_.x, t2_.y, t3_.x, t3_.y};                           \
    }

#define COMPUTE_H(A, hh)                                                       \
    _Pragma("unroll")                                                          \
    for (int m_ = 0; m_ < 2; ++m_) {                                           \
        f32x4 s0 = MFMA8S(A[m_], kf8[0], zed);                                 \
        f32x4 s1 = MFMA8S(A[m_], kf8[1], zed);                                 \
        f32x4 s2 = MFMA8S(A[m_], kf8[2], zed);                                 \
        f32x4 s3 = MFMA8S(A[m_], kf8[3], zed);                                 \
        f32x4 wv = *(const f32x4*)&wlds[hh][wm * 32 + m_ * 16 + rsub];         \
        _Pragma("unroll")                                                      \
        for (int rr_ = 0; rr_ < 4; ++rr_) {                                    \
            acc[m_][0][rr_] += wv[rr_] * fmaxf(s0[rr_], 0.0f);                 \
            acc[m_][1][rr_] += wv[rr_] * fmaxf(s1[rr_], 0.0f);                 \
            acc[m_][2][rr_] += wv[rr_] * fmaxf(s2[rr_], 0.0f);                 \
            acc[m_][3][rr_] += wv[rr_] * fmaxf(s3[rr_], 0.0f);                 \
        }                                                                      \
    }

__global__ __launch_bounds__(256)
void scores_mfma(const unsigned char* __restrict__ qfrag,
                 const unsigned char* __restrict__ kfrag,
                 const float* __restrict__ wT, float* __restrict__ S) {
    const int bid = blockIdx.x;                  // 0..1055
    int u = (int)((sqrtf(4.f * bid + 1.f) - 1.f) * 0.5f);
    while ((u + 1) * (u + 2) <= bid) ++u;
    while (u * (u + 1) > bid) --u;
    int r_ = bid - u * (u + 1);                  // 0..2u+1
    const int byp = (r_ <= u) ? 2 * u : 2 * u + 1;
    const int jt  = (r_ <= u) ? r_ : r_ - (u + 1);
    __shared__ float wlds[64][64];
    const int tid = threadIdx.x;
    const int lane = tid & 63, wid = tid >> 6;
    const int wm = wid >> 1, wn = wid & 1;       // 2 x 2
    const int i0 = byp * 64, j0 = jt * 128;
    const f32x4 zed = {0.f, 0.f, 0.f, 0.f};
#pragma unroll
    for (int it = 0; it < 16; ++it) {
        int fid = it * 256 + tid;
        int hh = fid >> 6, rl = fid & 63;
        wlds[hh][rl] = wT[(size_t)hh * T_DIM + i0 + rl];
    }
    i32x8 kf8[4];
#pragma unroll
    for (int n = 0; n < 4; ++n) {
        int jg = (j0 >> 4) + wn * 4 + n;
        const unsigned char* kb = kfrag + ((size_t)jg * 4 * 64 + lane) * 8;
        int2 u0 = *(const int2*)(kb + 0 * 512);
        int2 u1 = *(const int2*)(kb + 1 * 512);
        int2 u2 = *(const int2*)(kb + 2 * 512);
        int2 u3 = *(const int2*)(kb + 3 * 512);
        kf8[n] = (i32x8){u0.x, u0.y, u1.x, u1.y, u2.x, u2.y, u3.x, u3.y};
    }
    __syncthreads();

    f32x4 acc[2][4];
#pragma unroll
    for (int m = 0; m < 2; m++)
#pragma unroll
        for (int n = 0; n < 4; n++) acc[m][n] = zed;

    const int rsub = (lane >> 4) << 2;
    const unsigned char* qb[2];
#pragma unroll
    for (int m = 0; m < 2; ++m) {
        int ig = byp * 4 + wm * 2 + m;
        qb[m] = qfrag + (size_t)ig * 64 * 2048 + lane * 8;
    }

    i32x8 a0[2], a1[2];
    LOAD_H(a0, 0)
    for (int h = 0; h < NH; h += 2) {
        LOAD_H(a1, h + 1)
        COMPUTE_H(a0, h)
        if (h + 2 < NH) { LOAD_H(a0, h + 2) }
        COMPUTE_H(a1, h + 1)
    }

    const int colc = lane & 15;
#pragma unroll
    for (int m = 0; m < 2; m++) {
#pragma unroll
        for (int n = 0; n < 4; n++) {
            int col = j0 + wn * 64 + n * 16 + colc;
#pragma unroll
            for (int rr = 0; rr < 4; rr++) {
                int row = i0 + wm * 32 + m * 16 + rsub + rr;
                float v = acc[m][n][rr];
                if (col > row) v = MASK_VAL;
                S[(size_t)row * T_DIM + col] = v;
            }
        }
    }
}

// ============================================================================
// topk v6: fully macro-unrolled bitonic (same network as verified v4/v5;
// round-15 counters showed runtime k/j loops cost ~2.5x the static instr
// estimate -- compile-time layers kill loop control + enable chain interleave)
// ============================================================================
__device__ __forceinline__ void ce(unsigned &x, unsigned &y, bool up) {
    unsigned lo = x < y ? x : y, hi = x < y ? y : x;
    x = up ? lo : hi; y = up ? hi : lo;
}
__device__ __forceinline__ unsigned cd(unsigned a, unsigned b, bool keep_lo) {
    unsigned lo = a < b ? a : b, hi = a < b ? b : a;
    return keep_lo ? lo : hi;
}

#define TK_SHFL(k, j) {                                                        \
    const bool kl_ = ((e0 & (k)) == 0u) ^ ((e0 & (j)) != 0u);                  \
    q0 = cd(q0, (unsigned)__shfl_xor((int)q0, (j) >> 2), kl_);                 \
    q1 = cd(q1, (unsigned)__shfl_xor((int)q1, (j) >> 2), kl_);                 \
    q2 = cd(q2, (unsigned)__shfl_xor((int)q2, (j) >> 2), kl_);                 \
    q3 = cd(q3, (unsigned)__shfl_xor((int)q3, (j) >> 2), kl_); }

#define TK_LDS(k, j) {                                                         \
    __syncthreads();                                                           \
    *(uint4*)&L[e0] = make_uint4(q0, q1, q2, q3);                              \
    __syncthreads();                                                           \
    uint4 p_ = *(uint4*)&L[e0 ^ (j)];                                          \
    const bool kl_ = ((e0 & (k)) == 0u) ^ ((e0 & (j)) != 0u);                  \
    q0 = cd(q0, p_.x, kl_); q1 = cd(q1, p_.y, kl_);                            \
    q2 = cd(q2, p_.z, kl_); q3 = cd(q3, p_.w, kl_); }

#define TK_REG(k) {                                                            \
    const bool up_ = ((e0 & (k)) == 0u);                                       \
    ce(q0, q2, up_); ce(q1, q3, up_);                                          \
    ce(q0, q1, up_); ce(q2, q3, up_); }

__global__ __launch_bounds__(1024)
void topk_kernel(const float* __restrict__ S, float* __restrict__ outIdx) {
    __shared__ unsigned lds[4096];
    const int bid = blockIdx.x;
    const int tid = threadIdx.x;

    unsigned q0, q1, q2, q3;
    int row; unsigned e0; unsigned* L;

    if (bid < 1024) {            // two short rows per block
        const int half = tid >> 9;
        row = bid * 2 + half;
        e0 = 4u * (tid & 511);
        L = &lds[half * 2048];
    } else {                     // one long row
        row = bid + 1024;
        e0 = 4u * tid;
        L = lds;
    }
    const unsigned N = (bid < 1024) ? 2048u : 4096u;

    {   // load + pack keys (masked p>row synthesized) + stages k=2,4
        float4 f = *(const float4*)(S + (size_t)row * T_DIM + e0);
        const float* fp = &f.x;
        unsigned qq[4];
#pragma unroll
        for (int e = 0; e < 4; ++e) {
            unsigned p = e0 + e;
            unsigned u = __float_as_uint(fp[e]);
            u = (u & 0x80000000u) ? ~u : (u | 0x80000000u);
            unsigned key = ((~u) & 0xFFFFF000u) | p;
            qq[e] = ((int)p > row) ? (0xFFFFF000u | p) : key;
        }
        q0 = qq[0]; q1 = qq[1]; q2 = qq[2]; q3 = qq[3];
        ce(q0, q1, true); ce(q2, q3, false);           // k=2
        bool up4 = (e0 & 4u) == 0;                     // k=4
        ce(q0, q2, up4); ce(q1, q3, up4);
        ce(q0, q1, up4); ce(q2, q3, up4);
    }

    // ---- fully unrolled stages k=8..2048 ----
    TK_SHFL(8u, 4u)                                             TK_REG(8u)
    TK_SHFL(16u, 8u)  TK_SHFL(16u, 4u)                          TK_REG(16u)
    TK_SHFL(32u, 16u) TK_SHFL(32u, 8u)  TK_SHFL(32u, 4u)        TK_REG(32u)
    TK_SHFL(64u, 32u) TK_SHFL(64u, 16u) TK_SHFL(64u, 8u)
    TK_SHFL(64u, 4u)                                            TK_REG(64u)
    TK_SHFL(128u, 64u) TK_SHFL(128u, 32u) TK_SHFL(128u, 16u)
    TK_SHFL(128u, 8u)  TK_SHFL(128u, 4u)                        TK_REG(128u)
    TK_SHFL(256u, 128u) TK_SHFL(256u, 64u) TK_SHFL(256u, 32u)
    TK_SHFL(256u, 16u)  TK_SHFL(256u, 8u)  TK_SHFL(256u, 4u)    TK_REG(256u)
    TK_LDS(512u, 256u)
    TK_SHFL(512u, 128u) TK_SHFL(512u, 64u) TK_SHFL(512u, 32u)
    TK_SHFL(512u, 16u)  TK_SHFL(512u, 8u)  TK_SHFL(512u, 4u)    TK_REG(512u)
    TK_LDS(1024u, 512u) TK_LDS(1024u, 256u)
    TK_SHFL(1024u, 128u) TK_SHFL(1024u, 64u) TK_SHFL(1024u, 32u)
    TK_SHFL(1024u, 16u)  TK_SHFL(1024u, 8u)  TK_SHFL(1024u, 4u) TK_REG(1024u)
    TK_LDS(2048u, 1024u) TK_LDS(2048u, 512u) TK_LDS(2048u, 256u)
    TK_SHFL(2048u, 128u) TK_SHFL(2048u, 64u) TK_SHFL(2048u, 32u)
    TK_SHFL(2048u, 16u)  TK_SHFL(2048u, 8u)  TK_SHFL(2048u, 4u) TK_REG(2048u)

    if (N == 4096u) {
        __syncthreads();
        *(uint4*)&lds[e0] = make_uint4(q0, q1, q2, q3);
        __syncthreads();
        const bool low = e0 < 2048u;
        if (low) {
            uint4 p = *(uint4*)&lds[e0 + 2048];
            q0 = q0 < p.x ? q0 : p.x; q1 = q1 < p.y ? q1 : p.y;
            q2 = q2 < p.z ? q2 : p.z; q3 = q3 < p.w ? q3 : p.w;
        }
#define TK_MLDS(j) {                                                           \
        __syncthreads();                                                       \
        if (low) *(uint4*)&lds[e0] = make_uint4(q0, q1, q2, q3);               \
        __syncthreads();                                                       \
        if (low) {                                                             \
            uint4 p_ = *(uint4*)&lds[e0 ^ (j)];                                \
            const bool kl_ = (e0 & (j)) == 0u;                                 \
            q0 = cd(q0, p_.x, kl_); q1 = cd(q1, p_.y, kl_);                    \
            q2 = cd(q2, p_.z, kl_); q3 = cd(q3, p_.w, kl_); } }
#define TK_MSHFL(j) {                                                          \
        const bool kl_ = (e0 & (j)) == 0u;                                     \
        q0 = cd(q0, (unsigned)__shfl_xor((int)q0, (j) >> 2), kl_);             \
        q1 = cd(q1, (unsigned)__shfl_xor((int)q1, (j) >> 2), kl_);             \
        q2 = cd(q2, (unsigned)__shfl_xor((int)q2, (j) >> 2), kl_);             \
        q3 = cd(q3, (unsigned)__shfl_xor((int)q3, (j) >> 2), kl_); }
        TK_MLDS(1024u) TK_MLDS(512u) TK_MLDS(256u)
        if (low) {
            TK_MSHFL(128u) TK_MSHFL(64u) TK_MSHFL(32u)
            TK_MSHFL(16u)  TK_MSHFL(8u)  TK_MSHFL(4u)
            ce(q0, q2, true); ce(q1, q3, true);
            ce(q0, q1, true); ce(q2, q3, true);
            float4 o = make_float4((float)(q0 & 0xFFFu), (float)(q1 & 0xFFFu),
                                   (float)(q2 & 0xFFFu), (float)(q3 & 0xFFFu));
            *(float4*)(outIdx + (size_t)row * TOPK_N + e0) = o;
        }
    } else {
        float4 o = make_float4((float)(q0 & 0xFFFu), (float)(q1 & 0xFFFu),
                               (float)(q2 & 0xFFFu), (float)(q3 & 0xFFFu));
        *(float4*)(outIdx + (size_t)row * TOPK_N + e0) = o;
    }
}

// ============================================================================
extern "C" void kernel_launch(void* const* d_in, const int* in_sizes, int n_in,
                              void* d_out, int out_size, void* d_ws, size_t ws_size,
                              hipStream_t stream) {
    const float* hs      = (const float*)d_in[0];
    const float* qr      = (const float*)d_in[1];
    const int*   pos     = (const int*)  d_in[2];
    const float* wq_b    = (const float*)d_in[3];
    const float* wk      = (const float*)d_in[4];
    const float* k_gamma = (const float*)d_in[5];
    const float* k_beta  = (const float*)d_in[6];
    const float* w_proj  = (const float*)d_in[7];

    float* out     = (float*)d_out;
    float* out_idx = out;
    float* S       = out + (size_t)T_DIM * TOPK_N;

    char* wsp = (char*)d_ws;
    unsigned char*  qfrag  = (unsigned char*)wsp;  wsp += (size_t)67108864;
    unsigned short* hsfrag = (unsigned short*)qfrag;  // alias: hs consumed before qfrag written
    unsigned char*  qrfrag = (unsigned char*)wsp;  wsp += (size_t)12582912;
    unsigned char*  wqfrag = (unsigned char*)wsp;  wsp += (size_t)25165824;
    unsigned short* wkwfrag= (unsigned short*)wsp; wsp += (size_t)2752512;
    float*          part   = (float*)wsp;          wsp += (size_t)12582912;
    float*          wT     = (float*)wsp;          wsp += (size_t)1048576;
    unsigned char*  kfrag  = (unsigned char*)wsp;  wsp += (size_t)1048576;
    float2*         tab    = (float2*)wsp;         wsp += (size_t)1048576;

    rope_tab_kernel<<<512, 256, 0, stream>>>(pos, tab);
    conv_afrag <<<3584, 256, 0, stream>>>(hs, hsfrag, HSZ, 224, 28);
    conv_wkw   <<<672,  256, 0, stream>>>(wk, w_proj, wkwfrag);
    kw_gemm_mfma<<<1024, 256, 0, stream>>>(hsfrag, wkwfrag, part);
    reduce_w   <<<64,   256, 0, stream>>>(part, wT);
    ln_rope_k  <<<T_DIM / 4, 256, 0, stream>>>(part, tab, k_gamma, k_beta, kfrag);
    conv_qr_fp8<<<768,  256, 0, stream>>>(qr, qrfrag);
    conv_wq_fp8<<<1536, 256, 0, stream>>>(wq_b, wqfrag);
    q_gemm_mfma<<<2048, 256, 0, stream>>>(qrfrag, wqfrag, tab, qfrag);
    scores_mfma<<<1056, 256, 0, stream>>>(qfrag, kfrag, wT, S);
    topk_kernel<<<3072, 1024, 0, stream>>>(S, out_idx);
}